// Round 7
// baseline (463.776 us; speedup 1.0000x reference)
//
#include <hip/hip_runtime.h>

namespace {

constexpr int L = 10000;   // links
constexpr int F = 8;       // input features
constexpr int H = 64;      // hidden size

typedef __bf16 bf16x8 __attribute__((ext_vector_type(8)));
typedef float  f32x4  __attribute__((ext_vector_type(4)));

constexpr int JPB = 8;                 // links per block
constexpr int XH_LINK = 64 * 33 + 1;   // 2113 words: i-stride 33 (A-frag reads
                                        // 2-way = free), link-stride 2113

__device__ __forceinline__ float fsigmoid(float x) {
    return 1.0f / (1.0f + __expf(-x));
}
__device__ __forceinline__ float ftanh(float x) {
    return 2.0f / (1.0f + __expf(-2.0f * x)) - 1.0f;
}

// One wave per link. MFMA 16x16x32 bf16.
// A-frag: lane holds A[row=lane&15][k=(lane>>4)*8+e]
// B-frag: lane holds B[k=(lane>>4)*8+e][col=lane&15]
// D: col=lane&15, row=(lane>>4)*4+reg   [guide-verified m89]
//
// Occupancy design: LDS 75.8 KB -> 2 blocks/CU; waves_per_eu(4) -> VGPR<=128
// (live set ~110, no spill). 16 waves/CU with cross-block stage/compute overlap.
__global__ __attribute__((amdgpu_waves_per_eu(4))) __launch_bounds__(512)
void gcrnn_mfma(const float* __restrict__ hidden, const float* __restrict__ xin,
                const float* __restrict__ Wrh, const float* __restrict__ Brh,
                const float* __restrict__ Wri, const float* __restrict__ Bri,
                const float* __restrict__ Wuh, const float* __restrict__ Buh,
                const float* __restrict__ Wui, const float* __restrict__ Bui,
                const float* __restrict__ Wnh, const float* __restrict__ Bnh,
                const float* __restrict__ Wni, const float* __restrict__ Bni,
                float* __restrict__ out)
{
    // bijective XCD-chunked swizzle over 1250 workgroups (8 links each):
    // adjacent blocks (sharing output lines) land on the same XCD's L2.
    constexpr int NWG = L / JPB;               // 1250
    constexpr int q = NWG / 8, r = NWG % 8;    // 156, 2
    const int orig = blockIdx.x;
    const int xcd = orig & 7, idx = orig >> 3;
    const int wg = (xcd < r ? xcd * (q + 1) : r * (q + 1) + (xcd - r) * q) + idx;
    const int j0 = wg * JPB;

    __shared__ float sXh[JPB * XH_LINK];   // 67.6 KB; doubles as out staging
    __shared__ float sB[4 * JPB * 64];     // 8 KB (R/U biases pre-combined)

    const int tb = threadIdx.x;

    // ================= cooperative staging (32B segments, 2 adjacent blocks
    // complete each 64B line on the same XCD) ================================
    {
        const int jl = tb & 7;
        const int rq = tb >> 3;            // 0..63
        // Xh rows (b=c, i=rq)
#pragma unroll
        for (int c = 0; c < 32; ++c) {
            sXh[jl * XH_LINK + rq * 33 + c] =
                hidden[(size_t)(c * 64 + rq) * L + j0 + jl];
        }
        // biases (col = rq), R/U pre-combined
        const size_t o = (size_t)rq * L + j0 + jl;
        sB[0 * JPB * 64 + jl * 64 + rq] = Brh[o] + Bri[o];
        sB[1 * JPB * 64 + jl * 64 + rq] = Buh[o] + Bui[o];
        sB[2 * JPB * 64 + jl * 64 + rq] = Bnh[o];
        sB[3 * JPB * 64 + jl * 64 + rq] = Bni[o];
    }
    __syncthreads();

    // ================= per-wave per-link MFMA ================================
    const int lane = tb & 63;
    const int wv   = tb >> 6;              // wave owns link wv (0..7)
    const int j    = j0 + wv;
    const int lc   = lane & 15;
    const int grp  = lane >> 4;

    // A fragments from LDS (2-way bank access = free)
    bf16x8 aH[2][2];
    bf16x8 aI[2];
#pragma unroll
    for (int m = 0; m < 2; ++m) {
        const int b_ = m * 16 + lc;
#pragma unroll
        for (int ks = 0; ks < 2; ++ks)
#pragma unroll
            for (int e = 0; e < 8; ++e)
                aH[m][ks][e] = (__bf16)sXh[wv * XH_LINK + (ks * 32 + grp * 8 + e) * 33 + b_];
        // Xi direct from global (10 MB, cache-resident), K-padded to 32
        const size_t ibase = (size_t)b_ * F * L + j;
#pragma unroll
        for (int e = 0; e < 8; ++e) {
            float v = (grp == 0) ? xin[ibase + (size_t)e * L] : 0.0f;
            aI[m][e] = (__bf16)v;
        }
    }

    const float* WR = Wrh + (size_t)j * H * H;
    const float* WU = Wuh + (size_t)j * H * H;
    const float* WN = Wnh + (size_t)j * H * H;
    const float* IR = Wri + (size_t)j * F * H;
    const float* IU = Wui + (size_t)j * F * H;
    const float* IN = Wni + (size_t)j * F * H;

#pragma unroll
    for (int n = 0; n < 4; ++n) {
        const int col = n * 16 + lc;

        // B fragments straight from global f32 (4 full 64B lines per instr,
        // each weight line fetched exactly once)
        bf16x8 bR[2], bU[2], bN[2];
#pragma unroll
        for (int ks = 0; ks < 2; ++ks)
#pragma unroll
            for (int e = 0; e < 8; ++e) {
                const int i = ks * 32 + grp * 8 + e;
                bR[ks][e] = (__bf16)WR[i * H + col];
                bU[ks][e] = (__bf16)WU[i * H + col];
                bN[ks][e] = (__bf16)WN[i * H + col];
            }
        bf16x8 iR, iU, iN;
#pragma unroll
        for (int e = 0; e < 8; ++e) {
            float vr = 0.0f, vu = 0.0f, vn = 0.0f;
            if (grp == 0) {
                vr = IR[e * H + col];
                vu = IU[e * H + col];
                vn = IN[e * H + col];
            }
            iR[e] = (__bf16)vr; iU[e] = (__bf16)vu; iN[e] = (__bf16)vn;
        }

        // biases from LDS (same word across grp -> broadcast, free)
        const float biR  = sB[0 * JPB * 64 + wv * 64 + col];
        const float biU  = sB[1 * JPB * 64 + wv * 64 + col];
        const float biNH = sB[2 * JPB * 64 + wv * 64 + col];
        const float biNI = sB[3 * JPB * 64 + wv * 64 + col];

        // MFMAs: 4 gate accumulators x 2 m-tiles
        f32x4 accR[2], accU[2], accN[2], accNI[2];
#pragma unroll
        for (int m = 0; m < 2; ++m) {
            accR[m] = (f32x4){0.f, 0.f, 0.f, 0.f};
            accU[m] = (f32x4){0.f, 0.f, 0.f, 0.f};
            accN[m] = (f32x4){0.f, 0.f, 0.f, 0.f};
            accNI[m] = (f32x4){0.f, 0.f, 0.f, 0.f};
#pragma unroll
            for (int ks = 0; ks < 2; ++ks) {
                accR[m] = __builtin_amdgcn_mfma_f32_16x16x32_bf16(aH[m][ks], bR[ks], accR[m], 0, 0, 0);
                accU[m] = __builtin_amdgcn_mfma_f32_16x16x32_bf16(aH[m][ks], bU[ks], accU[m], 0, 0, 0);
                accN[m] = __builtin_amdgcn_mfma_f32_16x16x32_bf16(aH[m][ks], bN[ks], accN[m], 0, 0, 0);
            }
            accR[m]  = __builtin_amdgcn_mfma_f32_16x16x32_bf16(aI[m], iR, accR[m], 0, 0, 0);
            accU[m]  = __builtin_amdgcn_mfma_f32_16x16x32_bf16(aI[m], iU, accU[m], 0, 0, 0);
            accNI[m] = __builtin_amdgcn_mfma_f32_16x16x32_bf16(aI[m], iN, accNI[m], 0, 0, 0);
        }

        // epilogue: word (col*33+b_) is hidden(b_, i=col) on read and
        // out(b_, k=col) on write -- in-place, register-ordered, lane-private
#pragma unroll
        for (int m = 0; m < 2; ++m)
#pragma unroll
            for (int rr = 0; rr < 4; ++rr) {
                const int b_ = m * 16 + grp * 4 + rr;
                const int w = wv * XH_LINK + col * 33 + b_;
                const float h = sXh[w];
                const float rv = fsigmoid(accR[m][rr] + biR);
                const float uv = fsigmoid(accU[m][rr] + biU);
                const float nv = ftanh(rv * (accN[m][rr] + biNH) + accNI[m][rr] + biNI);
                sXh[w] = (1.0f - uv) * nv + uv * h;
            }
    }

    __syncthreads();

    // ================= cooperative writeout (32B segments; adjacent block
    // on the same XCD supplies the other half of each 64B line) =============
    {
        const int jl = tb & 7;
        const int rq = tb >> 3;            // k = rq
#pragma unroll
        for (int c = 0; c < 32; ++c) {     // b = c
            out[(size_t)(c * 64 + rq) * L + j0 + jl] =
                sXh[jl * XH_LINK + rq * 33 + c];
        }
    }
}

} // namespace

extern "C" void kernel_launch(void* const* d_in, const int* in_sizes, int n_in,
                              void* d_out, int out_size, void* d_ws, size_t ws_size,
                              hipStream_t stream) {
    const float* hidden = (const float*)d_in[0];
    const float* xin    = (const float*)d_in[1];
    const float* Wrh    = (const float*)d_in[2];
    const float* Brh    = (const float*)d_in[3];
    const float* Wri    = (const float*)d_in[4];
    const float* Bri    = (const float*)d_in[5];
    const float* Wuh    = (const float*)d_in[6];
    const float* Buh    = (const float*)d_in[7];
    const float* Wui    = (const float*)d_in[8];
    const float* Bui    = (const float*)d_in[9];
    const float* Wnh    = (const float*)d_in[10];
    const float* Bnh    = (const float*)d_in[11];
    const float* Wni    = (const float*)d_in[12];
    const float* Bni    = (const float*)d_in[13];
    float* out = (float*)d_out;

    gcrnn_mfma<<<L / JPB, 512, 0, stream>>>(hidden, xin,
                                            Wrh, Brh, Wri, Bri,
                                            Wuh, Buh, Wui, Bui,
                                            Wnh, Bnh, Wni, Bni,
                                            out);
}

// Round 8
// 346.170 us; speedup vs baseline: 1.3397x; 1.3397x over previous
//
#include <hip/hip_runtime.h>

namespace {

constexpr int L = 10000;   // links
constexpr int F = 8;       // input features
constexpr int H = 64;      // hidden size

typedef __bf16 bf16x8 __attribute__((ext_vector_type(8)));
typedef float  f32x4  __attribute__((ext_vector_type(4)));

constexpr int JPB = 8;                 // links per block
constexpr int XH_LINK = 64 * 33 + 1;   // 2113 words: i-stride 33 -> A-frag reads
                                        // 2-way (free), epilogue <=4-way

__device__ __forceinline__ float fsigmoid(float x) {
    return 1.0f / (1.0f + __expf(-x));
}
__device__ __forceinline__ float ftanh(float x) {
    return 2.0f / (1.0f + __expf(-2.0f * x)) - 1.0f;
}

// MFMA 16x16x32 bf16, one wave per link (each wave serially does 2 links).
// A-frag: lane holds A[row=lane&15][k=(lane>>4)*8+e]
// B-frag: lane holds B[k=(lane>>4)*8+e][col=lane&15]
// D: col=lane&15, row=(lane>>4)*4+reg   [guide-verified m89]
//
// Register design (the R5-R7 lesson): cap 256 via (256,2) -- NEVER demand
// occupancy the live set can't meet, spill costs 300+ MB of HBM. n-loop is
// unroll-1 so per-n B-frags/acc stay transient (~190 unified regs steady).
__global__ __launch_bounds__(256, 2)
void gcrnn_mfma(const float* __restrict__ hidden, const float* __restrict__ xin,
                const float* __restrict__ Wrh, const float* __restrict__ Brh,
                const float* __restrict__ Wri, const float* __restrict__ Bri,
                const float* __restrict__ Wuh, const float* __restrict__ Buh,
                const float* __restrict__ Wui, const float* __restrict__ Bui,
                const float* __restrict__ Wnh, const float* __restrict__ Bnh,
                const float* __restrict__ Wni, const float* __restrict__ Bni,
                float* __restrict__ out)
{
    // bijective XCD-chunked swizzle over 1250 workgroups (8 links each):
    // adjacent blocks (sharing 64B lines) land on the same XCD's L2.
    constexpr int NWG = L / JPB;               // 1250
    constexpr int q = NWG / 8, r = NWG % 8;    // 156, 2
    const int orig = blockIdx.x;
    const int xcd = orig & 7, idx = orig >> 3;
    const int wg = (xcd < r ? xcd * (q + 1) : r * (q + 1) + (xcd - r) * q) + idx;
    const int j0 = wg * JPB;

    __shared__ float sXh[JPB * XH_LINK];   // 67.6 KB; doubles as out staging
    __shared__ float sB[4 * JPB * 64];     // 8 KB (R/U biases pre-combined)

    const int tb = threadIdx.x;

    // ===== cooperative staging (32B segments; same-XCD neighbor block
    // supplies the other half of each 64B line) ==============================
    {
        const int jl = tb & 7;
        const int rq = tb >> 3;            // 0..31
#pragma unroll
        for (int h2 = 0; h2 < 2; ++h2) {
            const int i = h2 * 32 + rq;
            // Xh rows (b=c, i): lanes span 8 consecutive j
#pragma unroll
            for (int c = 0; c < 32; ++c) {
                sXh[jl * XH_LINK + i * 33 + c] =
                    hidden[(size_t)(c * 64 + i) * L + j0 + jl];
            }
            // biases (col = i), R/U pre-combined
            const size_t o = (size_t)i * L + j0 + jl;
            sB[0 * JPB * 64 + jl * 64 + i] = Brh[o] + Bri[o];
            sB[1 * JPB * 64 + jl * 64 + i] = Buh[o] + Bui[o];
            sB[2 * JPB * 64 + jl * 64 + i] = Bnh[o];
            sB[3 * JPB * 64 + jl * 64 + i] = Bni[o];
        }
    }
    __syncthreads();

    // ===== per-wave MFMA: each of the 4 waves handles 2 links serially ======
    const int lane = tb & 63;
    const int wid  = tb >> 6;              // 0..3
    const int lc   = lane & 15;
    const int grp  = lane >> 4;

#pragma unroll 1
    for (int half = 0; half < 2; ++half) {
        const int wv = wid + half * 4;     // link slot 0..7
        const int j  = j0 + wv;

        // A fragments from LDS (2-way bank access = free)
        bf16x8 aH[2][2];
        bf16x8 aI[2];
#pragma unroll
        for (int m = 0; m < 2; ++m) {
            const int b_ = m * 16 + lc;
#pragma unroll
            for (int ks = 0; ks < 2; ++ks)
#pragma unroll
                for (int e = 0; e < 8; ++e)
                    aH[m][ks][e] = (__bf16)sXh[wv * XH_LINK + (ks * 32 + grp * 8 + e) * 33 + b_];
            // Xi direct from global (10 MB, cache-resident), K-padded to 32
            const size_t ibase = (size_t)b_ * F * L + j;
#pragma unroll
            for (int e = 0; e < 8; ++e) {
                float v = (grp == 0) ? xin[ibase + (size_t)e * L] : 0.0f;
                aI[m][e] = (__bf16)v;
            }
        }

        const float* WR = Wrh + (size_t)j * H * H;
        const float* WU = Wuh + (size_t)j * H * H;
        const float* WN = Wnh + (size_t)j * H * H;
        const float* IR = Wri + (size_t)j * F * H;
        const float* IU = Wui + (size_t)j * F * H;
        const float* IN = Wni + (size_t)j * F * H;

#pragma unroll 1
        for (int n = 0; n < 4; ++n) {
            const int col = n * 16 + lc;

            // B fragments straight from global f32 (4 full 64B lines per
            // instr, each weight line fetched exactly once)
            bf16x8 bR[2], bU[2], bN[2];
#pragma unroll
            for (int ks = 0; ks < 2; ++ks)
#pragma unroll
                for (int e = 0; e < 8; ++e) {
                    const int i = ks * 32 + grp * 8 + e;
                    bR[ks][e] = (__bf16)WR[i * H + col];
                    bU[ks][e] = (__bf16)WU[i * H + col];
                    bN[ks][e] = (__bf16)WN[i * H + col];
                }
            bf16x8 iR, iU, iN;
#pragma unroll
            for (int e = 0; e < 8; ++e) {
                float vr = 0.0f, vu = 0.0f, vn = 0.0f;
                if (grp == 0) {
                    vr = IR[e * H + col];
                    vu = IU[e * H + col];
                    vn = IN[e * H + col];
                }
                iR[e] = (__bf16)vr; iU[e] = (__bf16)vu; iN[e] = (__bf16)vn;
            }

            // biases from LDS (same word across grp -> broadcast)
            const float biR  = sB[0 * JPB * 64 + wv * 64 + col];
            const float biU  = sB[1 * JPB * 64 + wv * 64 + col];
            const float biNH = sB[2 * JPB * 64 + wv * 64 + col];
            const float biNI = sB[3 * JPB * 64 + wv * 64 + col];

            // MFMAs: 4 gate accumulators x 2 m-tiles
            f32x4 accR[2], accU[2], accN[2], accNI[2];
#pragma unroll
            for (int m = 0; m < 2; ++m) {
                accR[m] = (f32x4){0.f, 0.f, 0.f, 0.f};
                accU[m] = (f32x4){0.f, 0.f, 0.f, 0.f};
                accN[m] = (f32x4){0.f, 0.f, 0.f, 0.f};
                accNI[m] = (f32x4){0.f, 0.f, 0.f, 0.f};
#pragma unroll
                for (int ks = 0; ks < 2; ++ks) {
                    accR[m] = __builtin_amdgcn_mfma_f32_16x16x32_bf16(aH[m][ks], bR[ks], accR[m], 0, 0, 0);
                    accU[m] = __builtin_amdgcn_mfma_f32_16x16x32_bf16(aH[m][ks], bU[ks], accU[m], 0, 0, 0);
                    accN[m] = __builtin_amdgcn_mfma_f32_16x16x32_bf16(aH[m][ks], bN[ks], accN[m], 0, 0, 0);
                }
                accR[m]  = __builtin_amdgcn_mfma_f32_16x16x32_bf16(aI[m], iR, accR[m], 0, 0, 0);
                accU[m]  = __builtin_amdgcn_mfma_f32_16x16x32_bf16(aI[m], iU, accU[m], 0, 0, 0);
                accNI[m] = __builtin_amdgcn_mfma_f32_16x16x32_bf16(aI[m], iN, accNI[m], 0, 0, 0);
            }

            // epilogue: word (col*33+b_) is hidden(b_, i=col) on read and
            // out(b_, k=col) on write -- in-place, register-ordered, private
#pragma unroll
            for (int m = 0; m < 2; ++m)
#pragma unroll
                for (int rr = 0; rr < 4; ++rr) {
                    const int b_ = m * 16 + grp * 4 + rr;
                    const int w = wv * XH_LINK + col * 33 + b_;
                    const float h = sXh[w];
                    const float rv = fsigmoid(accR[m][rr] + biR);
                    const float uv = fsigmoid(accU[m][rr] + biU);
                    const float nv = ftanh(rv * (accN[m][rr] + biNH) + accNI[m][rr] + biNI);
                    sXh[w] = (1.0f - uv) * nv + uv * h;
                }
        }
    }

    __syncthreads();

    // ===== cooperative writeout (32B segments; same-XCD neighbor block
    // completes each 64B line) ===============================================
    {
        const int jl = tb & 7;
        const int rq = tb >> 3;            // 0..31
#pragma unroll
        for (int h2 = 0; h2 < 2; ++h2) {
            const int k = h2 * 32 + rq;
#pragma unroll
            for (int c = 0; c < 32; ++c) { // b = c
                out[(size_t)(c * 64 + k) * L + j0 + jl] =
                    sXh[jl * XH_LINK + k * 33 + c];
            }
        }
    }
}

} // namespace

extern "C" void kernel_launch(void* const* d_in, const int* in_sizes, int n_in,
                              void* d_out, int out_size, void* d_ws, size_t ws_size,
                              hipStream_t stream) {
    const float* hidden = (const float*)d_in[0];
    const float* xin    = (const float*)d_in[1];
    const float* Wrh    = (const float*)d_in[2];
    const float* Brh    = (const float*)d_in[3];
    const float* Wri    = (const float*)d_in[4];
    const float* Bri    = (const float*)d_in[5];
    const float* Wuh    = (const float*)d_in[6];
    const float* Buh    = (const float*)d_in[7];
    const float* Wui    = (const float*)d_in[8];
    const float* Bui    = (const float*)d_in[9];
    const float* Wnh    = (const float*)d_in[10];
    const float* Bnh    = (const float*)d_in[11];
    const float* Wni    = (const float*)d_in[12];
    const float* Bni    = (const float*)d_in[13];
    float* out = (float*)d_out;

    gcrnn_mfma<<<L / JPB, 256, 0, stream>>>(hidden, xin,
                                            Wrh, Brh, Wri, Bri,
                                            Wuh, Buh, Wui, Bui,
                                            Wnh, Bnh, Wni, Bni,
                                            out);
}

// Round 9
// 295.405 us; speedup vs baseline: 1.5700x; 1.1718x over previous
//
#include <hip/hip_runtime.h>

namespace {

constexpr int L = 10000;   // links
constexpr int F = 8;       // input features
constexpr int H = 64;      // hidden size

typedef __bf16 bf16x8 __attribute__((ext_vector_type(8)));
typedef float  f32x4  __attribute__((ext_vector_type(4)));

// ---- LDS word-offsets (f32/u32 words) ----
// Hidden W, packed bf16 i-pairs: [gate][ipair=32][col=64] row-stride 68 words
//   word(g, ip, c) = g*2176 + ip*68 + c ; (i even -> lo16, i odd -> hi16)
// Input W packed: [gate][ipair=4][col=64], same row stride.
// Xh f32: [i=64][b=32] stride 33 (also reused in place for out staging).
constexpr int WROW     = 68;
constexpr int W_GATE   = 32 * WROW;            // 2176
constexpr int OFF_WIN  = 3 * W_GATE;           // 6528
constexpr int WIN_GATE = 4 * WROW;             // 272
constexpr int OFF_XH   = OFF_WIN + 3 * WIN_GATE;   // 7344
constexpr int LDS_WORDS = OFF_XH + 64 * 33;        // 9456 words = 37.8 KB

__device__ __forceinline__ float fsigmoid(float x) {
    return 1.0f / (1.0f + __expf(-x));
}
__device__ __forceinline__ float ftanh(float x) {
    return 2.0f / (1.0f + __expf(-2.0f * x)) - 1.0f;
}
__device__ __forceinline__ unsigned pack2(float lo, float hi) {
    __bf16 l = (__bf16)lo, h = (__bf16)hi;
    return (unsigned)__builtin_bit_cast(unsigned short, l) |
           ((unsigned)__builtin_bit_cast(unsigned short, h) << 16);
}

// One link per 256-thread block; wave w owns output col-tile n=w.
// MFMA 16x16x32 bf16:
//   A-frag: lane holds A[row=lane&15][k=(lane>>4)*8+e]
//   B-frag: lane holds B[k=(lane>>4)*8+e][col=lane&15]
//   D:      col=lane&15, row=(lane>>4)*4+reg    [guide-verified m89]
// Weights reach LDS via dwordx4 global loads (16B/lane -- the ~6 TB/s path;
// R4/R8 proved per-lane dword fragments cap at ~2 TB/s).
__global__ __launch_bounds__(256, 4)
void gcrnn_mfma(const float* __restrict__ hidden, const float* __restrict__ xin,
                const float* __restrict__ Wrh, const float* __restrict__ Brh,
                const float* __restrict__ Wri, const float* __restrict__ Bri,
                const float* __restrict__ Wuh, const float* __restrict__ Buh,
                const float* __restrict__ Wui, const float* __restrict__ Bui,
                const float* __restrict__ Wnh, const float* __restrict__ Bnh,
                const float* __restrict__ Wni, const float* __restrict__ Bni,
                float* __restrict__ out)
{
    // XCD-chunked bijective swizzle (10000 % 8 == 0): consecutive j share an
    // XCD so the 16-j-wide activation/out lines are L2-merged.
    const int orig = blockIdx.x;
    const int j = (orig & 7) * (L / 8) + (orig >> 3);

    __shared__ float sL[LDS_WORDS];
    unsigned* sLu = (unsigned*)sL;

    const int tb = threadIdx.x;

    // ================= staging =================
    const float* Wh0 = Wrh + (size_t)j * H * H;
    const float* Wh1 = Wuh + (size_t)j * H * H;
    const float* Wh2 = Wnh + (size_t)j * H * H;
    const float* Wi0 = Wri + (size_t)j * F * H;
    const float* Wi1 = Wui + (size_t)j * F * H;
    const float* Wi2 = Wni + (size_t)j * F * H;
    {
        const int pr = tb >> 4;          // 0..15
        const int c0 = (tb & 15) * 4;    // col quad
        const float* Wg[3] = {Wh0, Wh1, Wh2};
#pragma unroll
        for (int g = 0; g < 3; ++g) {
#pragma unroll
            for (int it = 0; it < 2; ++it) {
                const int p = it * 16 + pr;              // i-pair row 0..31
                const f32x4 a = *(const f32x4*)(Wg[g] + (size_t)(2 * p) * H + c0);
                const f32x4 b = *(const f32x4*)(Wg[g] + (size_t)(2 * p + 1) * H + c0);
                uint4 w;
                w.x = pack2(a[0], b[0]);
                w.y = pack2(a[1], b[1]);
                w.z = pack2(a[2], b[2]);
                w.w = pack2(a[3], b[3]);
                *(uint4*)&sLu[g * W_GATE + p * WROW + c0] = w;
            }
        }
        if (tb < 64) {                    // input weights: 8 rows x 64 cols x 3
            const int p = tb >> 4;        // i-pair 0..3
            const int ci = (tb & 15) * 4;
            const float* Wig[3] = {Wi0, Wi1, Wi2};
#pragma unroll
            for (int g = 0; g < 3; ++g) {
                const f32x4 a = *(const f32x4*)(Wig[g] + (size_t)(2 * p) * H + ci);
                const f32x4 b = *(const f32x4*)(Wig[g] + (size_t)(2 * p + 1) * H + ci);
                uint4 w;
                w.x = pack2(a[0], b[0]);
                w.y = pack2(a[1], b[1]);
                w.z = pack2(a[2], b[2]);
                w.w = pack2(a[3], b[3]);
                *(uint4*)&sLu[OFF_WIN + g * WIN_GATE + p * WROW + ci] = w;
            }
        }
        // Xh f32 (scattered dwords; lines shared with 15 adjacent-j blocks)
#pragma unroll
        for (int it = 0; it < 8; ++it) {
            const int idx = tb + 256 * it;
            const int b = idx & 31, i = idx >> 5;
            sL[OFF_XH + i * 33 + b] = hidden[(size_t)(b * H + i) * L + j];
        }
    }
    __syncthreads();

    // ================= per-wave compute: wave = one 16-col n-tile ===========
    const int lane = tb & 63;
    const int n    = tb >> 6;            // 0..3
    const int lc   = lane & 15;
    const int grp  = lane >> 4;
    const int col  = n * 16 + lc;

    // A fragments (read BEFORE the barrier that allows in-place sXh writes)
    bf16x8 aH[2][2];
    bf16x8 aI[2];
#pragma unroll
    for (int m = 0; m < 2; ++m) {
        const int b_ = m * 16 + lc;
#pragma unroll
        for (int ks = 0; ks < 2; ++ks)
#pragma unroll
            for (int e = 0; e < 8; ++e)
                aH[m][ks][e] = (__bf16)sL[OFF_XH + (ks * 32 + grp * 8 + e) * 33 + b_];
        const size_t ibase = (size_t)b_ * F * L + j;
#pragma unroll
        for (int e = 0; e < 8; ++e) {
            const float v = (grp == 0) ? xin[ibase + (size_t)e * L] : 0.0f;
            aI[m][e] = (__bf16)v;
        }
    }
    __syncthreads();   // all waves' A-reads complete before any sXh overwrite

    // biases for this lane's column (issued early, overlap frag reads)
    const size_t ko = (size_t)col * L + j;
    const float biR  = Brh[ko] + Bri[ko];
    const float biU  = Buh[ko] + Bui[ko];
    const float biNH = Bnh[ko];
    const float biNI = Bni[ko];

    // B fragments from packed LDS: 4 x b32 per (gate, ks), 2-way banks (free)
    auto rdH = [&](int g, int ks) -> bf16x8 {
        uint4 t;
        t.x = sLu[g * W_GATE + (ks * 16 + grp * 4 + 0) * WROW + col];
        t.y = sLu[g * W_GATE + (ks * 16 + grp * 4 + 1) * WROW + col];
        t.z = sLu[g * W_GATE + (ks * 16 + grp * 4 + 2) * WROW + col];
        t.w = sLu[g * W_GATE + (ks * 16 + grp * 4 + 3) * WROW + col];
        return __builtin_bit_cast(bf16x8, t);
    };
    auto rdI = [&](int g) -> bf16x8 {
        uint4 t;   // only grp==0 holds real k (aI is zero elsewhere anyway)
        t.x = (grp == 0) ? sLu[OFF_WIN + g * WIN_GATE + 0 * WROW + col] : 0u;
        t.y = (grp == 0) ? sLu[OFF_WIN + g * WIN_GATE + 1 * WROW + col] : 0u;
        t.z = (grp == 0) ? sLu[OFF_WIN + g * WIN_GATE + 2 * WROW + col] : 0u;
        t.w = (grp == 0) ? sLu[OFF_WIN + g * WIN_GATE + 3 * WROW + col] : 0u;
        return __builtin_bit_cast(bf16x8, t);
    };

    const bf16x8 fR0 = rdH(0, 0), fR1 = rdH(0, 1);
    const bf16x8 fU0 = rdH(1, 0), fU1 = rdH(1, 1);
    const bf16x8 fN0 = rdH(2, 0), fN1 = rdH(2, 1);
    const bf16x8 fRI = rdI(0), fUI = rdI(1), fNI = rdI(2);

    f32x4 accR[2], accU[2], accN[2], accNI[2];
#pragma unroll
    for (int m = 0; m < 2; ++m) {
        accR[m]  = (f32x4){0.f, 0.f, 0.f, 0.f};
        accU[m]  = (f32x4){0.f, 0.f, 0.f, 0.f};
        accN[m]  = (f32x4){0.f, 0.f, 0.f, 0.f};
        accNI[m] = (f32x4){0.f, 0.f, 0.f, 0.f};
        accR[m] = __builtin_amdgcn_mfma_f32_16x16x32_bf16(aH[m][0], fR0, accR[m], 0, 0, 0);
        accR[m] = __builtin_amdgcn_mfma_f32_16x16x32_bf16(aH[m][1], fR1, accR[m], 0, 0, 0);
        accU[m] = __builtin_amdgcn_mfma_f32_16x16x32_bf16(aH[m][0], fU0, accU[m], 0, 0, 0);
        accU[m] = __builtin_amdgcn_mfma_f32_16x16x32_bf16(aH[m][1], fU1, accU[m], 0, 0, 0);
        accN[m] = __builtin_amdgcn_mfma_f32_16x16x32_bf16(aH[m][0], fN0, accN[m], 0, 0, 0);
        accN[m] = __builtin_amdgcn_mfma_f32_16x16x32_bf16(aH[m][1], fN1, accN[m], 0, 0, 0);
        accR[m]  = __builtin_amdgcn_mfma_f32_16x16x32_bf16(aI[m], fRI, accR[m], 0, 0, 0);
        accU[m]  = __builtin_amdgcn_mfma_f32_16x16x32_bf16(aI[m], fUI, accU[m], 0, 0, 0);
        accNI[m] = __builtin_amdgcn_mfma_f32_16x16x32_bf16(aI[m], fNI, accNI[m], 0, 0, 0);
    }

    // epilogue: LDS word (col*33+b_) is hidden(b_, i=col) on read and
    // out(b_, k=col) on write -- in place; cols are wave/lane-private.
#pragma unroll
    for (int m = 0; m < 2; ++m)
#pragma unroll
        for (int rr = 0; rr < 4; ++rr) {
            const int b_ = m * 16 + grp * 4 + rr;
            const int w = OFF_XH + col * 33 + b_;
            const float h = sL[w];
            const float rv = fsigmoid(accR[m][rr] + biR);
            const float uv = fsigmoid(accU[m][rr] + biU);
            const float nv = ftanh(rv * (accN[m][rr] + biNH) + accNI[m][rr] + biNI);
            sL[w] = (1.0f - uv) * nv + uv * h;
        }

    __syncthreads();

    // ================= cooperative writeout (scattered dwords; 16 adjacent-j
    // blocks on the same XCD complete each 64B line in L2) ===================
#pragma unroll
    for (int it = 0; it < 8; ++it) {
        const int idx = tb + 256 * it;
        const int b = idx & 31, k = idx >> 5;
        out[(size_t)(b * H + k) * L + j] = sL[OFF_XH + k * 33 + b];
    }
}

} // namespace

extern "C" void kernel_launch(void* const* d_in, const int* in_sizes, int n_in,
                              void* d_out, int out_size, void* d_ws, size_t ws_size,
                              hipStream_t stream) {
    const float* hidden = (const float*)d_in[0];
    const float* xin    = (const float*)d_in[1];
    const float* Wrh    = (const float*)d_in[2];
    const float* Brh    = (const float*)d_in[3];
    const float* Wri    = (const float*)d_in[4];
    const float* Bri    = (const float*)d_in[5];
    const float* Wuh    = (const float*)d_in[6];
    const float* Buh    = (const float*)d_in[7];
    const float* Wui    = (const float*)d_in[8];
    const float* Bui    = (const float*)d_in[9];
    const float* Wnh    = (const float*)d_in[10];
    const float* Bnh    = (const float*)d_in[11];
    const float* Wni    = (const float*)d_in[12];
    const float* Bni    = (const float*)d_in[13];
    float* out = (float*)d_out;

    gcrnn_mfma<<<L, 256, 0, stream>>>(hidden, xin,
                                      Wrh, Brh, Wri, Bri,
                                      Wuh, Buh, Wui, Bui,
                                      Wnh, Bnh, Wni, Bni,
                                      out);
}

// Round 10
// 266.028 us; speedup vs baseline: 1.7433x; 1.1104x over previous
//
#include <hip/hip_runtime.h>

namespace {

constexpr int L = 10000;   // links
constexpr int F = 8;       // input features
constexpr int H = 64;      // hidden size

typedef __bf16 bf16x8 __attribute__((ext_vector_type(8)));
typedef float  f32x4  __attribute__((ext_vector_type(4)));

__device__ __forceinline__ float fsigmoid(float x) {
    return 1.0f / (1.0f + __expf(-x));
}
__device__ __forceinline__ float ftanh(float x) {
    return 2.0f / (1.0f + __expf(-2.0f * x)) - 1.0f;
}
__device__ __forceinline__ unsigned pack2(float lo, float hi) {
    __bf16 l = (__bf16)lo, h = (__bf16)hi;
    return (unsigned)__builtin_bit_cast(unsigned short, l) |
           ((unsigned)__builtin_bit_cast(unsigned short, h) << 16);
}
__device__ __forceinline__ float unbf(unsigned short u) {
    return (float)__builtin_bit_cast(__bf16, u);
}

// ---------------- workspace layout (bytes) ----------------
// PA: per link 384 uint4 (6 KB)  = A-frags in exact MFMA lane order
//     slots s=0..3: aH[m=s>>1][ks=s&1]; s=4,5: aI[m] (grp!=0 zero-padded)
// PB: per link 256 f32 (1 KB)    = [g=R,U,NH,NI][col]
// PN: per link 512 f32x4 (8 KB)  = tanh-output "new", [s'=n*2+m][lane][rr]
// PU: per link 512 uint2 (4 KB)  = sigmoid "update" bf16, same order
constexpr size_t PA_OFF = 0;
constexpr size_t PB_OFF = PA_OFF + (size_t)L * 6144;    //  61,440,000
constexpr size_t PN_OFF = PB_OFF + (size_t)L * 1024;    //  71,680,000
constexpr size_t PU_OFF = PN_OFF + (size_t)L * 8192;    // 153,600,000
constexpr size_t WS_NEED = PU_OFF + (size_t)L * 4096;   // 194,560,000

// =====================================================================
// Pass 1: pack A-fragments + biases. Thread map (q x 16 j-inner lanes):
// every global read touches full 64B lines (16 consecutive j per line),
// every PA write is 4 consecutive dwordx4 per j = full lines.
// =====================================================================
__global__ __launch_bounds__(256)
void pre_pack(const float* __restrict__ hidden, const float* __restrict__ xin,
              const float* __restrict__ Brh, const float* __restrict__ Bri,
              const float* __restrict__ Buh, const float* __restrict__ Bui,
              const float* __restrict__ Bnh, const float* __restrict__ Bni,
              uint4* __restrict__ PA, float* __restrict__ PB)
{
    const int jt = blockIdx.x >> 2;        // j-tile of 16
    const int quarter = blockIdx.x & 3;    // q-range quarter
    const int j0 = jt * 16;
    const int jl = threadIdx.x & 15;
    const int qs = threadIdx.x >> 4;
    const int j = j0 + jl;

    const int qlo = quarter * 112, qhi = qlo + 112;   // 448 q-units total
    for (int q = qlo + qs; q < qhi; q += 16) {
        if (q < 384) {
            // ---- A-fragment dwordx4 q: slot s, frag-lane ql
            const int s = q >> 6, ql = q & 63;
            const int grp = ql >> 4, lc = ql & 15;
            float v[8];
            if (s < 4) {
                const int m = s >> 1, ks = s & 1;
                const int b = m * 16 + lc;
                const int i0 = ks * 32 + grp * 8;
                const size_t base = ((size_t)b * H + i0) * L + j;
#pragma unroll
                for (int e = 0; e < 8; ++e) v[e] = hidden[base + (size_t)e * L];
            } else {
                const int m = s - 4;
                const int b = m * 16 + lc;
#pragma unroll
                for (int e = 0; e < 8; ++e)
                    v[e] = (grp == 0) ? xin[((size_t)b * F + e) * L + j] : 0.0f;
            }
            uint4 w;
            w.x = pack2(v[0], v[1]); w.y = pack2(v[2], v[3]);
            w.z = pack2(v[4], v[5]); w.w = pack2(v[6], v[7]);
            PA[(size_t)j * 384 + q] = w;
        } else {
            // ---- bias f32x4: word w0 in [0,256)
            const int w0 = (q - 384) * 4;
            const int g = w0 >> 6, k0 = w0 & 63;
            float v[4];
#pragma unroll
            for (int e = 0; e < 4; ++e) {
                const size_t o = (size_t)(k0 + e) * L + j;
                if (g == 0)      v[e] = Brh[o] + Bri[o];
                else if (g == 1) v[e] = Buh[o] + Bui[o];
                else if (g == 2) v[e] = Bnh[o];
                else             v[e] = Bni[o];
            }
            *(f32x4*)&PB[(size_t)j * 256 + w0] = (f32x4){v[0], v[1], v[2], v[3]};
        }
    }
}

// =====================================================================
// Main: one link per 256-thread block; wave n owns col-tile n.
// LDS = weights only (29.4 KB). All global accesses dwordx4-class.
// One barrier. Writes packed n (f32) + u (bf16) -- blend happens in post.
// =====================================================================
constexpr int WROW     = 68;
constexpr int W_GATE   = 32 * WROW;              // 2176 words
constexpr int OFF_WIN  = 3 * W_GATE;             // 6528
constexpr int WIN_GATE = 4 * WROW;               // 272
constexpr int LDS_WORDS = OFF_WIN + 3 * WIN_GATE;  // 7344 words = 29.4 KB

__global__ __launch_bounds__(256, 4)
void gcrnn_main(const uint4* __restrict__ PA, const float* __restrict__ PB,
                const float* __restrict__ Wrh, const float* __restrict__ Wuh,
                const float* __restrict__ Wnh, const float* __restrict__ Wri,
                const float* __restrict__ Wui, const float* __restrict__ Wni,
                f32x4* __restrict__ PN, uint2* __restrict__ PU)
{
    const int j = blockIdx.x;      // all traffic block-private: no swizzle needed

    __shared__ float sL[LDS_WORDS];
    unsigned* sLu = (unsigned*)sL;

    const int tb = threadIdx.x;

    // ---- stage weights (dwordx4, bf16-packed i-pairs) ----
    {
        const int pr = tb >> 4;          // 0..15
        const int c0 = (tb & 15) * 4;    // col quad
        const float* Wg[3] = {Wrh + (size_t)j * H * H,
                              Wuh + (size_t)j * H * H,
                              Wnh + (size_t)j * H * H};
#pragma unroll
        for (int g = 0; g < 3; ++g) {
#pragma unroll
            for (int it = 0; it < 2; ++it) {
                const int p = it * 16 + pr;
                const f32x4 a = *(const f32x4*)(Wg[g] + (size_t)(2 * p) * H + c0);
                const f32x4 b = *(const f32x4*)(Wg[g] + (size_t)(2 * p + 1) * H + c0);
                uint4 w;
                w.x = pack2(a[0], b[0]); w.y = pack2(a[1], b[1]);
                w.z = pack2(a[2], b[2]); w.w = pack2(a[3], b[3]);
                *(uint4*)&sLu[g * W_GATE + p * WROW + c0] = w;
            }
        }
        if (tb < 64) {
            const int p = tb >> 4;
            const int ci = (tb & 15) * 4;
            const float* Wig[3] = {Wri + (size_t)j * F * H,
                                   Wui + (size_t)j * F * H,
                                   Wni + (size_t)j * F * H};
#pragma unroll
            for (int g = 0; g < 3; ++g) {
                const f32x4 a = *(const f32x4*)(Wig[g] + (size_t)(2 * p) * H + ci);
                const f32x4 b = *(const f32x4*)(Wig[g] + (size_t)(2 * p + 1) * H + ci);
                uint4 w;
                w.x = pack2(a[0], b[0]); w.y = pack2(a[1], b[1]);
                w.z = pack2(a[2], b[2]); w.w = pack2(a[3], b[3]);
                *(uint4*)&sLu[OFF_WIN + g * WIN_GATE + p * WROW + ci] = w;
            }
        }
    }

    // ---- A-fragments: contiguous dwordx4 per lane (packed by pre_pack) ----
    const int lane = tb & 63;
    const int n    = tb >> 6;
    const int lc   = lane & 15;
    const int grp  = lane >> 4;
    const int col  = n * 16 + lc;

    const uint4* pa = PA + (size_t)j * 384;
    bf16x8 aH[2][2], aI[2];
#pragma unroll
    for (int m = 0; m < 2; ++m) {
#pragma unroll
        for (int ks = 0; ks < 2; ++ks)
            aH[m][ks] = __builtin_bit_cast(bf16x8, pa[(m * 2 + ks) * 64 + lane]);
        aI[m] = __builtin_bit_cast(bf16x8, pa[(4 + m) * 64 + lane]);
    }

    // biases (coalesced within each wave: 64 consecutive words per gate)
    const float* pb = PB + (size_t)j * 256;
    const float biR  = pb[col];
    const float biU  = pb[64 + col];
    const float biNH = pb[128 + col];
    const float biNI = pb[192 + col];

    __syncthreads();

    // ---- B-fragments from packed LDS ----
    auto rdH = [&](int g, int ks) -> bf16x8 {
        uint4 t;
        t.x = sLu[g * W_GATE + (ks * 16 + grp * 4 + 0) * WROW + col];
        t.y = sLu[g * W_GATE + (ks * 16 + grp * 4 + 1) * WROW + col];
        t.z = sLu[g * W_GATE + (ks * 16 + grp * 4 + 2) * WROW + col];
        t.w = sLu[g * W_GATE + (ks * 16 + grp * 4 + 3) * WROW + col];
        return __builtin_bit_cast(bf16x8, t);
    };
    auto rdI = [&](int g) -> bf16x8 {
        uint4 t;
        t.x = (grp == 0) ? sLu[OFF_WIN + g * WIN_GATE + 0 * WROW + col] : 0u;
        t.y = (grp == 0) ? sLu[OFF_WIN + g * WIN_GATE + 1 * WROW + col] : 0u;
        t.z = (grp == 0) ? sLu[OFF_WIN + g * WIN_GATE + 2 * WROW + col] : 0u;
        t.w = (grp == 0) ? sLu[OFF_WIN + g * WIN_GATE + 3 * WROW + col] : 0u;
        return __builtin_bit_cast(bf16x8, t);
    };

    const bf16x8 fR0 = rdH(0, 0), fR1 = rdH(0, 1);
    const bf16x8 fU0 = rdH(1, 0), fU1 = rdH(1, 1);
    const bf16x8 fN0 = rdH(2, 0), fN1 = rdH(2, 1);
    const bf16x8 fRI = rdI(0), fUI = rdI(1), fNI = rdI(2);

    f32x4 accR[2], accU[2], accN[2], accNI[2];
#pragma unroll
    for (int m = 0; m < 2; ++m) {
        accR[m]  = (f32x4){0.f, 0.f, 0.f, 0.f};
        accU[m]  = (f32x4){0.f, 0.f, 0.f, 0.f};
        accN[m]  = (f32x4){0.f, 0.f, 0.f, 0.f};
        accNI[m] = (f32x4){0.f, 0.f, 0.f, 0.f};
        accR[m] = __builtin_amdgcn_mfma_f32_16x16x32_bf16(aH[m][0], fR0, accR[m], 0, 0, 0);
        accR[m] = __builtin_amdgcn_mfma_f32_16x16x32_bf16(aH[m][1], fR1, accR[m], 0, 0, 0);
        accU[m] = __builtin_amdgcn_mfma_f32_16x16x32_bf16(aH[m][0], fU0, accU[m], 0, 0, 0);
        accU[m] = __builtin_amdgcn_mfma_f32_16x16x32_bf16(aH[m][1], fU1, accU[m], 0, 0, 0);
        accN[m] = __builtin_amdgcn_mfma_f32_16x16x32_bf16(aH[m][0], fN0, accN[m], 0, 0, 0);
        accN[m] = __builtin_amdgcn_mfma_f32_16x16x32_bf16(aH[m][1], fN1, accN[m], 0, 0, 0);
        accR[m]  = __builtin_amdgcn_mfma_f32_16x16x32_bf16(aI[m], fRI, accR[m], 0, 0, 0);
        accU[m]  = __builtin_amdgcn_mfma_f32_16x16x32_bf16(aI[m], fUI, accU[m], 0, 0, 0);
        accNI[m] = __builtin_amdgcn_mfma_f32_16x16x32_bf16(aI[m], fNI, accNI[m], 0, 0, 0);
    }

    // ---- epilogue: packed stores, no scatter, no extra barrier ----
#pragma unroll
    for (int m = 0; m < 2; ++m) {
        f32x4 nv4;
        float uv4[4];
#pragma unroll
        for (int rr = 0; rr < 4; ++rr) {
            const float rv = fsigmoid(accR[m][rr] + biR);
            uv4[rr] = fsigmoid(accU[m][rr] + biU);
            nv4[rr] = ftanh(rv * (accN[m][rr] + biNH) + accNI[m][rr] + biNI);
        }
        const int q = (n * 2 + m) * 64 + lane;
        PN[(size_t)j * 512 + q] = nv4;
        uint2 uu;
        uu.x = pack2(uv4[0], uv4[1]);
        uu.y = pack2(uv4[2], uv4[3]);
        PU[(size_t)j * 512 + q] = uu;
    }
}

// =====================================================================
// Pass 3: blend + transpose back. (q x 16 j-inner) map: packed reads and
// the hidden/out accesses are all full-64B-line wave transactions.
// =====================================================================
__global__ __launch_bounds__(256)
void post_blend(const f32x4* __restrict__ PN, const uint2* __restrict__ PU,
                const float* __restrict__ hidden, float* __restrict__ out)
{
    const int jt = blockIdx.x >> 2;
    const int quarter = blockIdx.x & 3;
    const int j0 = jt * 16;
    const int jl = threadIdx.x & 15;
    const int qs = threadIdx.x >> 4;
    const int j = j0 + jl;

    const int qlo = quarter * 128, qhi = qlo + 128;   // 512 q-units total
    for (int q = qlo + qs; q < qhi; q += 16) {
        const int sp = q >> 6, lane = q & 63;
        const int n = sp >> 1, m = sp & 1;
        const int grp = lane >> 4, lc = lane & 15;
        const int k = n * 16 + lc;
        const int b0 = m * 16 + grp * 4;

        const f32x4 nn = PN[(size_t)j * 512 + q];
        const uint2 uu = PU[(size_t)j * 512 + q];
        float u[4];
        u[0] = unbf((unsigned short)(uu.x & 0xffff));
        u[1] = unbf((unsigned short)(uu.x >> 16));
        u[2] = unbf((unsigned short)(uu.y & 0xffff));
        u[3] = unbf((unsigned short)(uu.y >> 16));
#pragma unroll
        for (int rr = 0; rr < 4; ++rr) {
            const size_t o = ((size_t)(b0 + rr) * H + k) * L + j;
            out[o] = (1.0f - u[rr]) * nn[rr] + u[rr] * hidden[o];
        }
    }
}

// =====================================================================
// Fallback (R9 kernel, 295 us): used only if ws_size < WS_NEED.
// =====================================================================
constexpr int FB_OFF_XH   = LDS_WORDS;                  // 7344
constexpr int FB_LDS_WORDS = FB_OFF_XH + 64 * 33;       // 9456 words

__global__ __launch_bounds__(256, 4)
void gcrnn_fallback(const float* __restrict__ hidden, const float* __restrict__ xin,
                    const float* __restrict__ Wrh, const float* __restrict__ Brh,
                    const float* __restrict__ Wri, const float* __restrict__ Bri,
                    const float* __restrict__ Wuh, const float* __restrict__ Buh,
                    const float* __restrict__ Wui, const float* __restrict__ Bui,
                    const float* __restrict__ Wnh, const float* __restrict__ Bnh,
                    const float* __restrict__ Wni, const float* __restrict__ Bni,
                    float* __restrict__ out)
{
    const int orig = blockIdx.x;
    const int j = (orig & 7) * (L / 8) + (orig >> 3);

    __shared__ float sL[FB_LDS_WORDS];
    unsigned* sLu = (unsigned*)sL;
    const int tb = threadIdx.x;

    {
        const int pr = tb >> 4;
        const int c0 = (tb & 15) * 4;
        const float* Wg[3] = {Wrh + (size_t)j * H * H, Wuh + (size_t)j * H * H,
                              Wnh + (size_t)j * H * H};
#pragma unroll
        for (int g = 0; g < 3; ++g) {
#pragma unroll
            for (int it = 0; it < 2; ++it) {
                const int p = it * 16 + pr;
                const f32x4 a = *(const f32x4*)(Wg[g] + (size_t)(2 * p) * H + c0);
                const f32x4 b = *(const f32x4*)(Wg[g] + (size_t)(2 * p + 1) * H + c0);
                uint4 w;
                w.x = pack2(a[0], b[0]); w.y = pack2(a[1], b[1]);
                w.z = pack2(a[2], b[2]); w.w = pack2(a[3], b[3]);
                *(uint4*)&sLu[g * W_GATE + p * WROW + c0] = w;
            }
        }
        if (tb < 64) {
            const int p = tb >> 4;
            const int ci = (tb & 15) * 4;
            const float* Wig[3] = {Wri + (size_t)j * F * H, Wui + (size_t)j * F * H,
                                   Wni + (size_t)j * F * H};
#pragma unroll
            for (int g = 0; g < 3; ++g) {
                const f32x4 a = *(const f32x4*)(Wig[g] + (size_t)(2 * p) * H + ci);
                const f32x4 b = *(const f32x4*)(Wig[g] + (size_t)(2 * p + 1) * H + ci);
                uint4 w;
                w.x = pack2(a[0], b[0]); w.y = pack2(a[1], b[1]);
                w.z = pack2(a[2], b[2]); w.w = pack2(a[3], b[3]);
                *(uint4*)&sLu[OFF_WIN + g * WIN_GATE + p * WROW + ci] = w;
            }
        }
#pragma unroll
        for (int it = 0; it < 8; ++it) {
            const int idx = tb + 256 * it;
            const int b = idx & 31, i = idx >> 5;
            sL[FB_OFF_XH + i * 33 + b] = hidden[(size_t)(b * H + i) * L + j];
        }
    }
    __syncthreads();

    const int lane = tb & 63;
    const int n    = tb >> 6;
    const int lc   = lane & 15;
    const int grp  = lane >> 4;
    const int col  = n * 16 + lc;

    bf16x8 aH[2][2], aI[2];
#pragma unroll
    for (int m = 0; m < 2; ++m) {
        const int b_ = m * 16 + lc;
#pragma unroll
        for (int ks = 0; ks < 2; ++ks)
#pragma unroll
            for (int e = 0; e < 8; ++e)
                aH[m][ks][e] = (__bf16)sL[FB_OFF_XH + (ks * 32 + grp * 8 + e) * 33 + b_];
        const size_t ibase = (size_t)b_ * F * L + j;
#pragma unroll
        for (int e = 0; e < 8; ++e) {
            const float v = (grp == 0) ? xin[ibase + (size_t)e * L] : 0.0f;
            aI[m][e] = (__bf16)v;
        }
    }
    __syncthreads();

    const size_t ko = (size_t)col * L + j;
    const float biR  = Brh[ko] + Bri[ko];
    const float biU  = Buh[ko] + Bui[ko];
    const float biNH = Bnh[ko];
    const float biNI = Bni[ko];

    auto rdH = [&](int g, int ks) -> bf16x8 {
        uint4 t;
        t.x = sLu[g * W_GATE + (ks * 16 + grp * 4 + 0) * WROW + col];
        t.y = sLu[g * W_GATE + (ks * 16 + grp * 4 + 1) * WROW + col];
        t.z = sLu[g * W_GATE + (ks * 16 + grp * 4 + 2) * WROW + col];
        t.w = sLu[g * W_GATE + (ks * 16 + grp * 4 + 3) * WROW + col];
        return __builtin_bit_cast(bf16x8, t);
    };
    auto rdI = [&](int g) -> bf16x8 {
        uint4 t;
        t.x = (grp == 0) ? sLu[OFF_WIN + g * WIN_GATE + 0 * WROW + col] : 0u;
        t.y = (grp == 0) ? sLu[OFF_WIN + g * WIN_GATE + 1 * WROW + col] : 0u;
        t.z = (grp == 0) ? sLu[OFF_WIN + g * WIN_GATE + 2 * WROW + col] : 0u;
        t.w = (grp == 0) ? sLu[OFF_WIN + g * WIN_GATE + 3 * WROW + col] : 0u;
        return __builtin_bit_cast(bf16x8, t);
    };

    const bf16x8 fR0 = rdH(0, 0), fR1 = rdH(0, 1);
    const bf16x8 fU0 = rdH(1, 0), fU1 = rdH(1, 1);
    const bf16x8 fN0 = rdH(2, 0), fN1 = rdH(2, 1);
    const bf16x8 fRI = rdI(0), fUI = rdI(1), fNI = rdI(2);

    f32x4 accR[2], accU[2], accN[2], accNI[2];
#pragma unroll
    for (int m = 0; m < 2; ++m) {
        accR[m]  = (f32x4){0.f, 0.f, 0.f, 0.f};
        accU[m]  = (f32x4){0.f, 0.f, 0.f, 0.f};
        accN[m]  = (f32x4){0.f, 0.f, 0.f, 0.f};
        accNI[m] = (f32x4){0.f, 0.f, 0.f, 0.f};
        accR[m] = __builtin_amdgcn_mfma_f32_16x16x32_bf16(aH[m][0], fR0, accR[m], 0, 0, 0);
        accR[m] = __builtin_amdgcn_mfma_f32_16x16x32_bf16(aH[m][1], fR1, accR[m], 0, 0, 0);
        accU[m] = __builtin_amdgcn_mfma_f32_16x16x32_bf16(aH[m][0], fU0, accU[m], 0, 0, 0);
        accU[m] = __builtin_amdgcn_mfma_f32_16x16x32_bf16(aH[m][1], fU1, accU[m], 0, 0, 0);
        accN[m] = __builtin_amdgcn_mfma_f32_16x16x32_bf16(aH[m][0], fN0, accN[m], 0, 0, 0);
        accN[m] = __builtin_amdgcn_mfma_f32_16x16x32_bf16(aH[m][1], fN1, accN[m], 0, 0, 0);
        accR[m]  = __builtin_amdgcn_mfma_f32_16x16x32_bf16(aI[m], fRI, accR[m], 0, 0, 0);
        accU[m]  = __builtin_amdgcn_mfma_f32_16x16x32_bf16(aI[m], fUI, accU[m], 0, 0, 0);
        accNI[m] = __builtin_amdgcn_mfma_f32_16x16x32_bf16(aI[m], fNI, accNI[m], 0, 0, 0);
    }

#pragma unroll
    for (int m = 0; m < 2; ++m)
#pragma unroll
        for (int rr = 0; rr < 4; ++rr) {
            const int b_ = m * 16 + grp * 4 + rr;
            const int w = FB_OFF_XH + col * 33 + b_;
            const float h = sL[w];
            const float rv = fsigmoid(accR[m][rr] + biR);
            const float uv = fsigmoid(accU[m][rr] + biU);
            const float nv = ftanh(rv * (accN[m][rr] + biNH) + accNI[m][rr] + biNI);
            sL[w] = (1.0f - uv) * nv + uv * h;
        }
    __syncthreads();

#pragma unroll
    for (int it = 0; it < 8; ++it) {
        const int idx = tb + 256 * it;
        const int b = idx & 31, k = idx >> 5;
        out[(size_t)(b * H + k) * L + j] = sL[FB_OFF_XH + k * 33 + b];
    }
}

} // namespace

extern "C" void kernel_launch(void* const* d_in, const int* in_sizes, int n_in,
                              void* d_out, int out_size, void* d_ws, size_t ws_size,
                              hipStream_t stream) {
    const float* hidden = (const float*)d_in[0];
    const float* xin    = (const float*)d_in[1];
    const float* Wrh    = (const float*)d_in[2];
    const float* Brh    = (const float*)d_in[3];
    const float* Wri    = (const float*)d_in[4];
    const float* Bri    = (const float*)d_in[5];
    const float* Wuh    = (const float*)d_in[6];
    const float* Buh    = (const float*)d_in[7];
    const float* Wui    = (const float*)d_in[8];
    const float* Bui    = (const float*)d_in[9];
    const float* Wnh    = (const float*)d_in[10];
    const float* Bnh    = (const float*)d_in[11];
    const float* Wni    = (const float*)d_in[12];
    const float* Bni    = (const float*)d_in[13];
    float* out = (float*)d_out;

    if (ws_size >= WS_NEED) {
        char* ws = (char*)d_ws;
        uint4* PA = (uint4*)(ws + PA_OFF);
        float* PB = (float*)(ws + PB_OFF);
        f32x4* PN = (f32x4*)(ws + PN_OFF);
        uint2* PU = (uint2*)(ws + PU_OFF);

        pre_pack<<<(L / 16) * 4, 256, 0, stream>>>(hidden, xin,
                                                   Brh, Bri, Buh, Bui, Bnh, Bni,
                                                   PA, PB);
        gcrnn_main<<<L, 256, 0, stream>>>(PA, PB,
                                          Wrh, Wuh, Wnh, Wri, Wui, Wni,
                                          PN, PU);
        post_blend<<<(L / 16) * 4, 256, 0, stream>>>(PN, PU, hidden, out);
    } else {
        gcrnn_fallback<<<L, 256, 0, stream>>>(hidden, xin,
                                              Wrh, Brh, Wri, Bri,
                                              Wuh, Buh, Wui, Bui,
                                              Wnh, Bnh, Wni, Bni,
                                              out);
    }
}

// Round 11
// 240.984 us; speedup vs baseline: 1.9245x; 1.1039x over previous
//
#include <hip/hip_runtime.h>

namespace {

constexpr int L = 10000;   // links
constexpr int F = 8;       // input features
constexpr int H = 64;      // hidden size

typedef __bf16 bf16x8 __attribute__((ext_vector_type(8)));
typedef float  f32x4  __attribute__((ext_vector_type(4)));

__device__ __forceinline__ float fsigmoid(float x) {
    return 1.0f / (1.0f + __expf(-x));
}
__device__ __forceinline__ float ftanh(float x) {
    return 2.0f / (1.0f + __expf(-2.0f * x)) - 1.0f;
}
__device__ __forceinline__ unsigned pack2(float lo, float hi) {
    __bf16 l = (__bf16)lo, h = (__bf16)hi;
    return (unsigned)__builtin_bit_cast(unsigned short, l) |
           ((unsigned)__builtin_bit_cast(unsigned short, h) << 16);
}
__device__ __forceinline__ float unbf(unsigned short u) {
    return (float)__builtin_bit_cast(__bf16, u);
}

// ---------------- workspace layout (bytes) ----------------
// PA : per link 288 uint4 (4.5 KB): slots 0..255 = aH[m=s>>1][ks=s&1] in exact
//      MFMA lane order; slots 256..287 = aI densely packed (grp0 lanes only).
// PB : per link 256 f32 (1 KB) = [g=R,U,NH,NI][col] (R/U biases combined)
// PNU: per link 512 uint4 (8 KB) = {n01,n23,u01,u23} bf16-packed per (s,lane)
constexpr size_t PA_OFF  = 0;
constexpr size_t PB_OFF  = PA_OFF + (size_t)L * 4608;   //  46,080,000
constexpr size_t PNU_OFF = PB_OFF + (size_t)L * 1024;   //  56,320,000
constexpr size_t WS_NEED = PNU_OFF + (size_t)L * 8192;  // 138,240,000

// =====================================================================
// Pass 1: pack A-fragments + biases. (q x 16 j-inner lanes) map: every
// wave-level transaction (reads of hidden/xin/bias, writes of PA/PB)
// covers full 64B lines.  352 q-units = 256 aH + 32 aI + 64 bias-quads.
// =====================================================================
__global__ __launch_bounds__(256)
void pre_pack(const float* __restrict__ hidden, const float* __restrict__ xin,
              const float* __restrict__ Brh, const float* __restrict__ Bri,
              const float* __restrict__ Buh, const float* __restrict__ Bui,
              const float* __restrict__ Bnh, const float* __restrict__ Bni,
              uint4* __restrict__ PA, float* __restrict__ PB)
{
    const int jt = blockIdx.x >> 2;        // j-tile of 16
    const int quarter = blockIdx.x & 3;
    const int j0 = jt * 16;
    const int jl = threadIdx.x & 15;
    const int qs = threadIdx.x >> 4;
    const int j = j0 + jl;

    const int qlo = quarter * 88, qhi = qlo + 88;   // 352 q-units total
    for (int q = qlo + qs; q < qhi; q += 16) {
        if (q < 256) {
            // ---- aH fragment dwordx4: slot s, frag-lane ql
            const int s = q >> 6, ql = q & 63;
            const int grp = ql >> 4, lc = ql & 15;
            const int m = s >> 1, ks = s & 1;
            const int b = m * 16 + lc;
            const int i0 = ks * 32 + grp * 8;
            const size_t base = ((size_t)b * H + i0) * L + j;
            float v[8];
#pragma unroll
            for (int e = 0; e < 8; ++e) v[e] = hidden[base + (size_t)e * L];
            uint4 w;
            w.x = pack2(v[0], v[1]); w.y = pack2(v[2], v[3]);
            w.z = pack2(v[4], v[5]); w.w = pack2(v[6], v[7]);
            PA[(size_t)j * 288 + q] = w;
        } else if (q < 288) {
            // ---- aI dense (grp0 content only): t = m*16+lc
            const int t = q - 256;
            const int m = t >> 4, lc = t & 15;
            const int b = m * 16 + lc;
            float v[8];
#pragma unroll
            for (int e = 0; e < 8; ++e) v[e] = xin[((size_t)b * F + e) * L + j];
            uint4 w;
            w.x = pack2(v[0], v[1]); w.y = pack2(v[2], v[3]);
            w.z = pack2(v[4], v[5]); w.w = pack2(v[6], v[7]);
            PA[(size_t)j * 288 + q] = w;
        } else {
            // ---- bias f32x4: word w0 in [0,256)
            const int w0 = (q - 288) * 4;
            const int g = w0 >> 6, k0 = w0 & 63;
            float v[4];
#pragma unroll
            for (int e = 0; e < 4; ++e) {
                const size_t o = (size_t)(k0 + e) * L + j;
                if (g == 0)      v[e] = Brh[o] + Bri[o];
                else if (g == 1) v[e] = Buh[o] + Bui[o];
                else if (g == 2) v[e] = Bnh[o];
                else             v[e] = Bni[o];
            }
            *(f32x4*)&PB[(size_t)j * 256 + w0] = (f32x4){v[0], v[1], v[2], v[3]};
        }
    }
}

// =====================================================================
// Main: one link per 256-thread block; wave n owns col-tile n.
// LDS = weights only. PA/PB loads issued BEFORE the weight-stage burst so
// their latency hides under it. One barrier. Output = packed bf16 uint4.
// =====================================================================
constexpr int WROW     = 68;
constexpr int W_GATE   = 32 * WROW;                // 2176 words
constexpr int OFF_WIN  = 3 * W_GATE;               // 6528
constexpr int WIN_GATE = 4 * WROW;                 // 272
constexpr int LDS_WORDS = OFF_WIN + 3 * WIN_GATE;  // 7344 words = 29.4 KB

__global__ __launch_bounds__(256, 4)
void gcrnn_main(const uint4* __restrict__ PA, const float* __restrict__ PB,
                const float* __restrict__ Wrh, const float* __restrict__ Wuh,
                const float* __restrict__ Wnh, const float* __restrict__ Wri,
                const float* __restrict__ Wui, const float* __restrict__ Wni,
                uint4* __restrict__ PNU)
{
    const int j = blockIdx.x;

    __shared__ float sL[LDS_WORDS];
    unsigned* sLu = (unsigned*)sL;

    const int tb = threadIdx.x;
    const int lane = tb & 63;
    const int n    = tb >> 6;
    const int lc   = lane & 15;
    const int grp  = lane >> 4;
    const int col  = n * 16 + lc;

    // ---- issue A-frag + bias loads first (latency overlaps weight staging)
    const uint4* pa = PA + (size_t)j * 288;
    bf16x8 aH[2][2], aI[2];
#pragma unroll
    for (int m = 0; m < 2; ++m) {
#pragma unroll
        for (int ks = 0; ks < 2; ++ks)
            aH[m][ks] = __builtin_bit_cast(bf16x8, pa[(m * 2 + ks) * 64 + lane]);
        uint4 z = {0u, 0u, 0u, 0u};
        aI[m] = __builtin_bit_cast(bf16x8, (grp == 0) ? pa[256 + m * 16 + lc] : z);
    }
    const float* pb = PB + (size_t)j * 256;
    const float biR  = pb[col];
    const float biU  = pb[64 + col];
    const float biNH = pb[128 + col];
    const float biNI = pb[192 + col];

    // ---- stage weights (dwordx4, bf16-packed i-pairs) ----
    {
        const int pr = tb >> 4;          // 0..15
        const int c0 = (tb & 15) * 4;    // col quad
        const float* Wg[3] = {Wrh + (size_t)j * H * H,
                              Wuh + (size_t)j * H * H,
                              Wnh + (size_t)j * H * H};
#pragma unroll
        for (int g = 0; g < 3; ++g) {
#pragma unroll
            for (int it = 0; it < 2; ++it) {
                const int p = it * 16 + pr;
                const f32x4 a = *(const f32x4*)(Wg[g] + (size_t)(2 * p) * H + c0);
                const f32x4 b = *(const f32x4*)(Wg[g] + (size_t)(2 * p + 1) * H + c0);
                uint4 w;
                w.x = pack2(a[0], b[0]); w.y = pack2(a[1], b[1]);
                w.z = pack2(a[2], b[2]); w.w = pack2(a[3], b[3]);
                *(uint4*)&sLu[g * W_GATE + p * WROW + c0] = w;
            }
        }
        if (tb < 64) {
            const int p = tb >> 4;
            const int ci = (tb & 15) * 4;
            const float* Wig[3] = {Wri + (size_t)j * F * H,
                                   Wui + (size_t)j * F * H,
                                   Wni + (size_t)j * F * H};
#pragma unroll
            for (int g = 0; g < 3; ++g) {
                const f32x4 a = *(const f32x4*)(Wig[g] + (size_t)(2 * p) * H + ci);
                const f32x4 b = *(const f32x4*)(Wig[g] + (size_t)(2 * p + 1) * H + ci);
                uint4 w;
                w.x = pack2(a[0], b[0]); w.y = pack2(a[1], b[1]);
                w.z = pack2(a[2], b[2]); w.w = pack2(a[3], b[3]);
                *(uint4*)&sLu[OFF_WIN + g * WIN_GATE + p * WROW + ci] = w;
            }
        }
    }
    __syncthreads();

    // ---- B-fragments from packed LDS ----
    auto rdH = [&](int g, int ks) -> bf16x8 {
        uint4 t;
        t.x = sLu[g * W_GATE + (ks * 16 + grp * 4 + 0) * WROW + col];
        t.y = sLu[g * W_GATE + (ks * 16 + grp * 4 + 1) * WROW + col];
        t.z = sLu[g * W_GATE + (ks * 16 + grp * 4 + 2) * WROW + col];
        t.w = sLu[g * W_GATE + (ks * 16 + grp * 4 + 3) * WROW + col];
        return __builtin_bit_cast(bf16x8, t);
    };
    auto rdI = [&](int g) -> bf16x8 {
        uint4 t;
        t.x = (grp == 0) ? sLu[OFF_WIN + g * WIN_GATE + 0 * WROW + col] : 0u;
        t.y = (grp == 0) ? sLu[OFF_WIN + g * WIN_GATE + 1 * WROW + col] : 0u;
        t.z = (grp == 0) ? sLu[OFF_WIN + g * WIN_GATE + 2 * WROW + col] : 0u;
        t.w = (grp == 0) ? sLu[OFF_WIN + g * WIN_GATE + 3 * WROW + col] : 0u;
        return __builtin_bit_cast(bf16x8, t);
    };

    const bf16x8 fR0 = rdH(0, 0), fR1 = rdH(0, 1);
    const bf16x8 fU0 = rdH(1, 0), fU1 = rdH(1, 1);
    const bf16x8 fN0 = rdH(2, 0), fN1 = rdH(2, 1);
    const bf16x8 fRI = rdI(0), fUI = rdI(1), fNI = rdI(2);

    f32x4 accR[2], accU[2], accN[2], accNI[2];
#pragma unroll
    for (int m = 0; m < 2; ++m) {
        accR[m]  = (f32x4){0.f, 0.f, 0.f, 0.f};
        accU[m]  = (f32x4){0.f, 0.f, 0.f, 0.f};
        accN[m]  = (f32x4){0.f, 0.f, 0.f, 0.f};
        accNI[m] = (f32x4){0.f, 0.f, 0.f, 0.f};
        accR[m] = __builtin_amdgcn_mfma_f32_16x16x32_bf16(aH[m][0], fR0, accR[m], 0, 0, 0);
        accR[m] = __builtin_amdgcn_mfma_f32_16x16x32_bf16(aH[m][1], fR1, accR[m], 0, 0, 0);
        accU[m] = __builtin_amdgcn_mfma_f32_16x16x32_bf16(aH[m][0], fU0, accU[m], 0, 0, 0);
        accU[m] = __builtin_amdgcn_mfma_f32_16x16x32_bf16(aH[m][1], fU1, accU[m], 0, 0, 0);
        accN[m] = __builtin_amdgcn_mfma_f32_16x16x32_bf16(aH[m][0], fN0, accN[m], 0, 0, 0);
        accN[m] = __builtin_amdgcn_mfma_f32_16x16x32_bf16(aH[m][1], fN1, accN[m], 0, 0, 0);
        accR[m]  = __builtin_amdgcn_mfma_f32_16x16x32_bf16(aI[m], fRI, accR[m], 0, 0, 0);
        accU[m]  = __builtin_amdgcn_mfma_f32_16x16x32_bf16(aI[m], fUI, accU[m], 0, 0, 0);
        accNI[m] = __builtin_amdgcn_mfma_f32_16x16x32_bf16(aI[m], fNI, accNI[m], 0, 0, 0);
    }

    // ---- epilogue: one packed bf16 uint4 store per m ----
#pragma unroll
    for (int m = 0; m < 2; ++m) {
        float nv4[4], uv4[4];
#pragma unroll
        for (int rr = 0; rr < 4; ++rr) {
            const float rv = fsigmoid(accR[m][rr] + biR);
            uv4[rr] = fsigmoid(accU[m][rr] + biU);
            nv4[rr] = ftanh(rv * (accN[m][rr] + biNH) + accNI[m][rr] + biNI);
        }
        uint4 o;
        o.x = pack2(nv4[0], nv4[1]); o.y = pack2(nv4[2], nv4[3]);
        o.z = pack2(uv4[0], uv4[1]); o.w = pack2(uv4[2], uv4[3]);
        PNU[(size_t)j * 512 + (n * 2 + m) * 64 + lane] = o;
    }
}

// =====================================================================
// Pass 3: blend + transpose back, (q x 16 j-inner) line-perfect map.
// =====================================================================
__global__ __launch_bounds__(256)
void post_blend(const uint4* __restrict__ PNU,
                const float* __restrict__ hidden, float* __restrict__ out)
{
    const int jt = blockIdx.x >> 2;
    const int quarter = blockIdx.x & 3;
    const int j0 = jt * 16;
    const int jl = threadIdx.x & 15;
    const int qs = threadIdx.x >> 4;
    const int j = j0 + jl;

    const int qlo = quarter * 128, qhi = qlo + 128;   // 512 q-units
    for (int q = qlo + qs; q < qhi; q += 16) {
        const int sp = q >> 6, lane = q & 63;
        const int n = sp >> 1, m = sp & 1;
        const int grp = lane >> 4, lc = lane & 15;
        const int k = n * 16 + lc;
        const int b0 = m * 16 + grp * 4;

        const uint4 pp = PNU[(size_t)j * 512 + q];
        float nn[4], u[4];
        nn[0] = unbf((unsigned short)(pp.x & 0xffff));
        nn[1] = unbf((unsigned short)(pp.x >> 16));
        nn[2] = unbf((unsigned short)(pp.y & 0xffff));
        nn[3] = unbf((unsigned short)(pp.y >> 16));
        u[0]  = unbf((unsigned short)(pp.z & 0xffff));
        u[1]  = unbf((unsigned short)(pp.z >> 16));
        u[2]  = unbf((unsigned short)(pp.w & 0xffff));
        u[3]  = unbf((unsigned short)(pp.w >> 16));
#pragma unroll
        for (int rr = 0; rr < 4; ++rr) {
            const size_t o = ((size_t)(b0 + rr) * H + k) * L + j;
            out[o] = (1.0f - u[rr]) * nn[rr] + u[rr] * hidden[o];
        }
    }
}

// =====================================================================
// Fallback (R9 kernel, 295 us): used only if ws_size < WS_NEED.
// =====================================================================
constexpr int FB_OFF_XH    = LDS_WORDS;             // 7344
constexpr int FB_LDS_WORDS = FB_OFF_XH + 64 * 33;   // 9456 words

__global__ __launch_bounds__(256, 4)
void gcrnn_fallback(const float* __restrict__ hidden, const float* __restrict__ xin,
                    const float* __restrict__ Wrh, const float* __restrict__ Brh,
                    const float* __restrict__ Wri, const float* __restrict__ Bri,
                    const float* __restrict__ Wuh, const float* __restrict__ Buh,
                    const float* __restrict__ Wui, const float* __restrict__ Bui,
                    const float* __restrict__ Wnh, const float* __restrict__ Bnh,
                    const float* __restrict__ Wni, const float* __restrict__ Bni,
                    float* __restrict__ out)
{
    const int orig = blockIdx.x;
    const int j = (orig & 7) * (L / 8) + (orig >> 3);

    __shared__ float sL[FB_LDS_WORDS];
    unsigned* sLu = (unsigned*)sL;
    const int tb = threadIdx.x;

    {
        const int pr = tb >> 4;
        const int c0 = (tb & 15) * 4;
        const float* Wg[3] = {Wrh + (size_t)j * H * H, Wuh + (size_t)j * H * H,
                              Wnh + (size_t)j * H * H};
#pragma unroll
        for (int g = 0; g < 3; ++g) {
#pragma unroll
            for (int it = 0; it < 2; ++it) {
                const int p = it * 16 + pr;
                const f32x4 a = *(const f32x4*)(Wg[g] + (size_t)(2 * p) * H + c0);
                const f32x4 b = *(const f32x4*)(Wg[g] + (size_t)(2 * p + 1) * H + c0);
                uint4 w;
                w.x = pack2(a[0], b[0]); w.y = pack2(a[1], b[1]);
                w.z = pack2(a[2], b[2]); w.w = pack2(a[3], b[3]);
                *(uint4*)&sLu[g * W_GATE + p * WROW + c0] = w;
            }
        }
        if (tb < 64) {
            const int p = tb >> 4;
            const int ci = (tb & 15) * 4;
            const float* Wig[3] = {Wri + (size_t)j * F * H, Wui + (size_t)j * F * H,
                                   Wni + (size_t)j * F * H};
#pragma unroll
            for (int g = 0; g < 3; ++g) {
                const f32x4 a = *(const f32x4*)(Wig[g] + (size_t)(2 * p) * H + ci);
                const f32x4 b = *(const f32x4*)(Wig[g] + (size_t)(2 * p + 1) * H + ci);
                uint4 w;
                w.x = pack2(a[0], b[0]); w.y = pack2(a[1], b[1]);
                w.z = pack2(a[2], b[2]); w.w = pack2(a[3], b[3]);
                *(uint4*)&sLu[OFF_WIN + g * WIN_GATE + p * WROW + ci] = w;
            }
        }
#pragma unroll
        for (int it = 0; it < 8; ++it) {
            const int idx = tb + 256 * it;
            const int b = idx & 31, i = idx >> 5;
            sL[FB_OFF_XH + i * 33 + b] = hidden[(size_t)(b * H + i) * L + j];
        }
    }
    __syncthreads();

    const int lane = tb & 63;
    const int n    = tb >> 6;
    const int lc   = lane & 15;
    const int grp  = lane >> 4;
    const int col  = n * 16 + lc;

    bf16x8 aH[2][2], aI[2];
#pragma unroll
    for (int m = 0; m < 2; ++m) {
        const int b_ = m * 16 + lc;
#pragma unroll
        for (int ks = 0; ks < 2; ++ks)
#pragma unroll
            for (int e = 0; e < 8; ++e)
                aH[m][ks][e] = (__bf16)sL[FB_OFF_XH + (ks * 32 + grp * 8 + e) * 33 + b_];
        const size_t ibase = (size_t)b_ * F * L + j;
#pragma unroll
        for (int e = 0; e < 8; ++e) {
            const float v = (grp == 0) ? xin[ibase + (size_t)e * L] : 0.0f;
            aI[m][e] = (__bf16)v;
        }
    }
    __syncthreads();

    const size_t ko = (size_t)col * L + j;
    const float biR  = Brh[ko] + Bri[ko];
    const float biU  = Buh[ko] + Bui[ko];
    const float biNH = Bnh[ko];
    const float biNI = Bni[ko];

    auto rdH = [&](int g, int ks) -> bf16x8 {
        uint4 t;
        t.x = sLu[g * W_GATE + (ks * 16 + grp * 4 + 0) * WROW + col];
        t.y = sLu[g * W_GATE + (ks * 16 + grp * 4 + 1) * WROW + col];
        t.z = sLu[g * W_GATE + (ks * 16 + grp * 4 + 2) * WROW + col];
        t.w = sLu[g * W_GATE + (ks * 16 + grp * 4 + 3) * WROW + col];
        return __builtin_bit_cast(bf16x8, t);
    };
    auto rdI = [&](int g) -> bf16x8 {
        uint4 t;
        t.x = (grp == 0) ? sLu[OFF_WIN + g * WIN_GATE + 0 * WROW + col] : 0u;
        t.y = (grp == 0) ? sLu[OFF_WIN + g * WIN_GATE + 1 * WROW + col] : 0u;
        t.z = (grp == 0) ? sLu[OFF_WIN + g * WIN_GATE + 2 * WROW + col] : 0u;
        t.w = (grp == 0) ? sLu[OFF_WIN + g * WIN_GATE + 3 * WROW + col] : 0u;
        return __builtin_bit_cast(bf16x8, t);
    };

    const bf16x8 fR0 = rdH(0, 0), fR1 = rdH(0, 1);
    const bf16x8 fU0 = rdH(1, 0), fU1 = rdH(1, 1);
    const bf16x8 fN0 = rdH(2, 0), fN1 = rdH(2, 1);
    const bf16x8 fRI = rdI(0), fUI = rdI(1), fNI = rdI(2);

    f32x4 accR[2], accU[2], accN[2], accNI[2];
#pragma unroll
    for (int m = 0; m < 2; ++m) {
        accR[m]  = (f32x4){0.f, 0.f, 0.f, 0.f};
        accU[m]  = (f32x4){0.f, 0.f, 0.f, 0.f};
        accN[m]  = (f32x4){0.f, 0.f, 0.f, 0.f};
        accNI[m] = (f32x4){0.f, 0.f, 0.f, 0.f};
        accR[m] = __builtin_amdgcn_mfma_f32_16x16x32_bf16(aH[m][0], fR0, accR[m], 0, 0, 0);
        accR[m] = __builtin_amdgcn_mfma_f32_16x16x32_bf16(aH[m][1], fR1, accR[m], 0, 0, 0);
        accU[m] = __builtin_amdgcn_mfma_f32_16x16x32_bf16(aH[m][0], fU0, accU[m], 0, 0, 0);
        accU[m] = __builtin_amdgcn_mfma_f32_16x16x32_bf16(aH[m][1], fU1, accU[m], 0, 0, 0);
        accN[m] = __builtin_amdgcn_mfma_f32_16x16x32_bf16(aH[m][0], fN0, accN[m], 0, 0, 0);
        accN[m] = __builtin_amdgcn_mfma_f32_16x16x32_bf16(aH[m][1], fN1, accN[m], 0, 0, 0);
        accR[m]  = __builtin_amdgcn_mfma_f32_16x16x32_bf16(aI[m], fRI, accR[m], 0, 0, 0);
        accU[m]  = __builtin_amdgcn_mfma_f32_16x16x32_bf16(aI[m], fUI, accU[m], 0, 0, 0);
        accNI[m] = __builtin_amdgcn_mfma_f32_16x16x32_bf16(aI[m], fNI, accNI[m], 0, 0, 0);
    }

#pragma unroll
    for (int m = 0; m < 2; ++m)
#pragma unroll
        for (int rr = 0; rr < 4; ++rr) {
            const int b_ = m * 16 + grp * 4 + rr;
            const int w = FB_OFF_XH + col * 33 + b_;
            const float h = sL[w];
            const float rv = fsigmoid(accR[m][rr] + biR);
            const float uv = fsigmoid(accU[m][rr] + biU);
            const float nv = ftanh(rv * (accN[m][rr] + biNH) + accNI[m][rr] + biNI);
            sL[w] = (1.0f - uv) * nv + uv * h;
        }
    __syncthreads();

#pragma unroll
    for (int it = 0; it < 8; ++it) {
        const int idx = tb + 256 * it;
        const int b = idx & 31, k = idx >> 5;
        out[(size_t)(b * H + k) * L + j] = sL[FB_OFF_XH + k * 33 + b];
    }
}

} // namespace

extern "C" void kernel_launch(void* const* d_in, const int* in_sizes, int n_in,
                              void* d_out, int out_size, void* d_ws, size_t ws_size,
                              hipStream_t stream) {
    const float* hidden = (const float*)d_in[0];
    const float* xin    = (const float*)d_in[1];
    const float* Wrh    = (const float*)d_in[2];
    const float* Brh    = (const float*)d_in[3];
    const float* Wri    = (const float*)d_in[4];
    const float* Bri    = (const float*)d_in[5];
    const float* Wuh    = (const float*)d_in[6];
    const float* Buh    = (const float*)d_in[7];
    const float* Wui    = (const float*)d_in[8];
    const float* Bui    = (const float*)d_in[9];
    const float* Wnh    = (const float*)d_in[10];
    const float* Bnh    = (const float*)d_in[11];
    const float* Wni    = (const float*)d_in[12];
    const float* Bni    = (const float*)d_in[13];
    float* out = (float*)d_out;

    if (ws_size >= WS_NEED) {
        char* ws = (char*)d_ws;
        uint4* PA  = (uint4*)(ws + PA_OFF);
        float* PB  = (float*)(ws + PB_OFF);
        uint4* PNU = (uint4*)(ws + PNU_OFF);

        pre_pack<<<(L / 16) * 4, 256, 0, stream>>>(hidden, xin,
                                                   Brh, Bri, Buh, Bui, Bnh, Bni,
                                                   PA, PB);
        gcrnn_main<<<L, 256, 0, stream>>>(PA, PB,
                                          Wrh, Wuh, Wnh, Wri, Wui, Wni,
                                          PNU);
        post_blend<<<(L / 16) * 4, 256, 0, stream>>>(PNU, hidden, out);
    } else {
        gcrnn_fallback<<<L, 256, 0, stream>>>(hidden, xin,
                                              Wrh, Brh, Wri, Bri,
                                              Wuh, Buh, Wui, Bui,
                                              Wnh, Bnh, Wni, Bni,
                                              out);
    }
}

// Round 12
// 235.575 us; speedup vs baseline: 1.9687x; 1.0230x over previous
//
#include <hip/hip_runtime.h>

namespace {

constexpr int L = 10000;   // links
constexpr int F = 8;       // input features
constexpr int H = 64;      // hidden size

typedef __bf16 bf16x8 __attribute__((ext_vector_type(8)));
typedef float  f32x4  __attribute__((ext_vector_type(4)));

__device__ __forceinline__ float fsigmoid(float x) {
    return 1.0f / (1.0f + __expf(-x));
}
__device__ __forceinline__ float ftanh(float x) {
    return 2.0f / (1.0f + __expf(-2.0f * x)) - 1.0f;
}
__device__ __forceinline__ unsigned pack2(float lo, float hi) {
    __bf16 l = (__bf16)lo, h = (__bf16)hi;
    return (unsigned)__builtin_bit_cast(unsigned short, l) |
           ((unsigned)__builtin_bit_cast(unsigned short, h) << 16);
}
__device__ __forceinline__ float unbf(unsigned short u) {
    return (float)__builtin_bit_cast(__bf16, u);
}

// ---------------- workspace layout (bytes) ----------------
// PA : per link 288 uint4 (4.5 KB): slots 0..255 = aH[m=s>>1][ks=s&1] in exact
//      MFMA lane order; slots 256..287 = aI densely packed (grp0 lanes only).
// PB : per link 256 f32 (1 KB) = [g=R,U,NH,NI][col] (R/U biases combined)
// PNU: per link 512 uint4 (8 KB) = {n01,n23,u01,u23} bf16-packed per (s,lane)
constexpr size_t PA_OFF  = 0;
constexpr size_t PB_OFF  = PA_OFF + (size_t)L * 4608;   //  46,080,000
constexpr size_t PNU_OFF = PB_OFF + (size_t)L * 1024;   //  56,320,000
constexpr size_t WS_NEED = PNU_OFF + (size_t)L * 8192;  // 138,240,000

// =====================================================================
// Pass 1: pack A-fragments + biases. (q x 16 j-inner lanes) map: every
// wave-level transaction covers full 64B lines.
// =====================================================================
__global__ __launch_bounds__(256)
void pre_pack(const float* __restrict__ hidden, const float* __restrict__ xin,
              const float* __restrict__ Brh, const float* __restrict__ Bri,
              const float* __restrict__ Buh, const float* __restrict__ Bui,
              const float* __restrict__ Bnh, const float* __restrict__ Bni,
              uint4* __restrict__ PA, float* __restrict__ PB)
{
    const int jt = blockIdx.x >> 2;        // j-tile of 16
    const int quarter = blockIdx.x & 3;
    const int j0 = jt * 16;
    const int jl = threadIdx.x & 15;
    const int qs = threadIdx.x >> 4;
    const int j = j0 + jl;

    const int qlo = quarter * 88, qhi = qlo + 88;   // 352 q-units total
    for (int q = qlo + qs; q < qhi; q += 16) {
        if (q < 256) {
            const int s = q >> 6, ql = q & 63;
            const int grp = ql >> 4, lc = ql & 15;
            const int m = s >> 1, ks = s & 1;
            const int b = m * 16 + lc;
            const int i0 = ks * 32 + grp * 8;
            const size_t base = ((size_t)b * H + i0) * L + j;
            float v[8];
#pragma unroll
            for (int e = 0; e < 8; ++e) v[e] = hidden[base + (size_t)e * L];
            uint4 w;
            w.x = pack2(v[0], v[1]); w.y = pack2(v[2], v[3]);
            w.z = pack2(v[4], v[5]); w.w = pack2(v[6], v[7]);
            PA[(size_t)j * 288 + q] = w;
        } else if (q < 288) {
            const int t = q - 256;
            const int m = t >> 4, lc = t & 15;
            const int b = m * 16 + lc;
            float v[8];
#pragma unroll
            for (int e = 0; e < 8; ++e) v[e] = xin[((size_t)b * F + e) * L + j];
            uint4 w;
            w.x = pack2(v[0], v[1]); w.y = pack2(v[2], v[3]);
            w.z = pack2(v[4], v[5]); w.w = pack2(v[6], v[7]);
            PA[(size_t)j * 288 + q] = w;
        } else {
            const int w0 = (q - 288) * 4;
            const int g = w0 >> 6, k0 = w0 & 63;
            float v[4];
#pragma unroll
            for (int e = 0; e < 4; ++e) {
                const size_t o = (size_t)(k0 + e) * L + j;
                if (g == 0)      v[e] = Brh[o] + Bri[o];
                else if (g == 1) v[e] = Buh[o] + Bui[o];
                else if (g == 2) v[e] = Bnh[o];
                else             v[e] = Bni[o];
            }
            *(f32x4*)&PB[(size_t)j * 256 + w0] = (f32x4){v[0], v[1], v[2], v[3]};
        }
    }
}

// =====================================================================
// Main: one link per 256-thread block; wave n owns col-tile n.
// Staging is LOAD-ALL-THEN-PACK: 12 (+6) dwordx4 weight loads held in
// named registers so the whole burst is in flight at once (the R11
// lesson: __launch_bounds__(256,4) -> VGPR 48 -> 2-deep serialized
// staging at HBM latency). No min-occupancy demand: allocator may use
// ~150 VGPR; LDS 29.7 KB; ~12 waves/CU with a 12-deep load queue each.
// =====================================================================
constexpr int WROW     = 68;
constexpr int W_GATE   = 32 * WROW;                // 2176 words
constexpr int OFF_WIN  = 3 * W_GATE;               // 6528
constexpr int WIN_GATE = 4 * WROW;                 // 272
constexpr int LDS_WORDS = OFF_WIN + 3 * WIN_GATE;  // 7344 words = 29.4 KB

__global__ __launch_bounds__(256)
void gcrnn_main(const uint4* __restrict__ PA, const float* __restrict__ PB,
                const float* __restrict__ Wrh, const float* __restrict__ Wuh,
                const float* __restrict__ Wnh, const float* __restrict__ Wri,
                const float* __restrict__ Wui, const float* __restrict__ Wni,
                uint4* __restrict__ PNU)
{
    const int j = blockIdx.x;

    __shared__ float sL[LDS_WORDS];
    unsigned* sLu = (unsigned*)sL;

    const int tb = threadIdx.x;
    const int lane = tb & 63;
    const int n    = tb >> 6;
    const int lc   = lane & 15;
    const int grp  = lane >> 4;
    const int col  = n * 16 + lc;

    // ---- issue A-frag + bias loads first (latency hides under weight burst)
    const uint4* pa = PA + (size_t)j * 288;
    bf16x8 aH[2][2], aI[2];
#pragma unroll
    for (int m = 0; m < 2; ++m) {
#pragma unroll
        for (int ks = 0; ks < 2; ++ks)
            aH[m][ks] = __builtin_bit_cast(bf16x8, pa[(m * 2 + ks) * 64 + lane]);
        uint4 z = {0u, 0u, 0u, 0u};
        aI[m] = __builtin_bit_cast(bf16x8, (grp == 0) ? pa[256 + m * 16 + lc] : z);
    }
    const float* pb = PB + (size_t)j * 256;
    const float biR  = pb[col];
    const float biU  = pb[64 + col];
    const float biNH = pb[128 + col];
    const float biNI = pb[192 + col];

    // ---- weight staging: LOAD ALL into registers, THEN pack to LDS ----
    const int pr = tb >> 4;          // 0..15
    const int c0 = (tb & 15) * 4;    // col quad
    const float* WgH[3] = {Wrh + (size_t)j * H * H,
                           Wuh + (size_t)j * H * H,
                           Wnh + (size_t)j * H * H};
    f32x4 wa[6], wb[6];
#pragma unroll
    for (int g = 0; g < 3; ++g)
#pragma unroll
        for (int it = 0; it < 2; ++it) {
            const int p = it * 16 + pr;
            wa[g * 2 + it] = *(const f32x4*)(WgH[g] + (size_t)(2 * p) * H + c0);
            wb[g * 2 + it] = *(const f32x4*)(WgH[g] + (size_t)(2 * p + 1) * H + c0);
        }
    f32x4 ia[3], ib[3];
    const bool doI = (tb < 64);
    if (doI) {
        const int p = tb >> 4;            // 0..3
        const int ci = (tb & 15) * 4;
        const float* WgI[3] = {Wri + (size_t)j * F * H,
                               Wui + (size_t)j * F * H,
                               Wni + (size_t)j * F * H};
#pragma unroll
        for (int g = 0; g < 3; ++g) {
            ia[g] = *(const f32x4*)(WgI[g] + (size_t)(2 * p) * H + ci);
            ib[g] = *(const f32x4*)(WgI[g] + (size_t)(2 * p + 1) * H + ci);
        }
    }
    // pack + LDS write (loads drain progressively while packing)
#pragma unroll
    for (int gi = 0; gi < 6; ++gi) {
        const int g = gi >> 1;
        const int p = (gi & 1) * 16 + pr;
        uint4 w;
        w.x = pack2(wa[gi][0], wb[gi][0]);
        w.y = pack2(wa[gi][1], wb[gi][1]);
        w.z = pack2(wa[gi][2], wb[gi][2]);
        w.w = pack2(wa[gi][3], wb[gi][3]);
        *(uint4*)&sLu[g * W_GATE + p * WROW + c0] = w;
    }
    if (doI) {
        const int p = tb >> 4;
        const int ci = (tb & 15) * 4;
#pragma unroll
        for (int g = 0; g < 3; ++g) {
            uint4 w;
            w.x = pack2(ia[g][0], ib[g][0]);
            w.y = pack2(ia[g][1], ib[g][1]);
            w.z = pack2(ia[g][2], ib[g][2]);
            w.w = pack2(ia[g][3], ib[g][3]);
            *(uint4*)&sLu[OFF_WIN + g * WIN_GATE + p * WROW + ci] = w;
        }
    }
    __syncthreads();

    // ---- B-fragments from packed LDS ----
    auto rdH = [&](int g, int ks) -> bf16x8 {
        uint4 t;
        t.x = sLu[g * W_GATE + (ks * 16 + grp * 4 + 0) * WROW + col];
        t.y = sLu[g * W_GATE + (ks * 16 + grp * 4 + 1) * WROW + col];
        t.z = sLu[g * W_GATE + (ks * 16 + grp * 4 + 2) * WROW + col];
        t.w = sLu[g * W_GATE + (ks * 16 + grp * 4 + 3) * WROW + col];
        return __builtin_bit_cast(bf16x8, t);
    };
    auto rdI = [&](int g) -> bf16x8 {
        uint4 t;
        t.x = (grp == 0) ? sLu[OFF_WIN + g * WIN_GATE + 0 * WROW + col] : 0u;
        t.y = (grp == 0) ? sLu[OFF_WIN + g * WIN_GATE + 1 * WROW + col] : 0u;
        t.z = (grp == 0) ? sLu[OFF_WIN + g * WIN_GATE + 2 * WROW + col] : 0u;
        t.w = (grp == 0) ? sLu[OFF_WIN + g * WIN_GATE + 3 * WROW + col] : 0u;
        return __builtin_bit_cast(bf16x8, t);
    };

    const bf16x8 fR0 = rdH(0, 0), fR1 = rdH(0, 1);
    const bf16x8 fU0 = rdH(1, 0), fU1 = rdH(1, 1);
    const bf16x8 fN0 = rdH(2, 0), fN1 = rdH(2, 1);
    const bf16x8 fRI = rdI(0), fUI = rdI(1), fNI = rdI(2);

    f32x4 accR[2], accU[2], accN[2], accNI[2];
#pragma unroll
    for (int m = 0; m < 2; ++m) {
        accR[m]  = (f32x4){0.f, 0.f, 0.f, 0.f};
        accU[m]  = (f32x4){0.f, 0.f, 0.f, 0.f};
        accN[m]  = (f32x4){0.f, 0.f, 0.f, 0.f};
        accNI[m] = (f32x4){0.f, 0.f, 0.f, 0.f};
        accR[m] = __builtin_amdgcn_mfma_f32_16x16x32_bf16(aH[m][0], fR0, accR[m], 0, 0, 0);
        accR[m] = __builtin_amdgcn_mfma_f32_16x16x32_bf16(aH[m][1], fR1, accR[m], 0, 0, 0);
        accU[m] = __builtin_amdgcn_mfma_f32_16x16x32_bf16(aH[m][0], fU0, accU[m], 0, 0, 0);
        accU[m] = __builtin_amdgcn_mfma_f32_16x16x32_bf16(aH[m][1], fU1, accU[m], 0, 0, 0);
        accN[m] = __builtin_amdgcn_mfma_f32_16x16x32_bf16(aH[m][0], fN0, accN[m], 0, 0, 0);
        accN[m] = __builtin_amdgcn_mfma_f32_16x16x32_bf16(aH[m][1], fN1, accN[m], 0, 0, 0);
        accR[m]  = __builtin_amdgcn_mfma_f32_16x16x32_bf16(aI[m], fRI, accR[m], 0, 0, 0);
        accU[m]  = __builtin_amdgcn_mfma_f32_16x16x32_bf16(aI[m], fUI, accU[m], 0, 0, 0);
        accNI[m] = __builtin_amdgcn_mfma_f32_16x16x32_bf16(aI[m], fNI, accNI[m], 0, 0, 0);
    }

    // ---- epilogue: one packed bf16 uint4 store per m ----
#pragma unroll
    for (int m = 0; m < 2; ++m) {
        float nv4[4], uv4[4];
#pragma unroll
        for (int rr = 0; rr < 4; ++rr) {
            const float rv = fsigmoid(accR[m][rr] + biR);
            uv4[rr] = fsigmoid(accU[m][rr] + biU);
            nv4[rr] = ftanh(rv * (accN[m][rr] + biNH) + accNI[m][rr] + biNI);
        }
        uint4 o;
        o.x = pack2(nv4[0], nv4[1]); o.y = pack2(nv4[2], nv4[3]);
        o.z = pack2(uv4[0], uv4[1]); o.w = pack2(uv4[2], uv4[3]);
        PNU[(size_t)j * 512 + (n * 2 + m) * 64 + lane] = o;
    }
}

// =====================================================================
// Pass 3: blend + transpose back, (q x 16 j-inner) line-perfect map.
// =====================================================================
__global__ __launch_bounds__(256)
void post_blend(const uint4* __restrict__ PNU,
                const float* __restrict__ hidden, float* __restrict__ out)
{
    const int jt = blockIdx.x >> 2;
    const int quarter = blockIdx.x & 3;
    const int j0 = jt * 16;
    const int jl = threadIdx.x & 15;
    const int qs = threadIdx.x >> 4;
    const int j = j0 + jl;

    const int qlo = quarter * 128, qhi = qlo + 128;   // 512 q-units
    for (int q = qlo + qs; q < qhi; q += 16) {
        const int sp = q >> 6, lane = q & 63;
        const int n = sp >> 1, m = sp & 1;
        const int grp = lane >> 4, lc = lane & 15;
        const int k = n * 16 + lc;
        const int b0 = m * 16 + grp * 4;

        const uint4 pp = PNU[(size_t)j * 512 + q];
        float nn[4], u[4];
        nn[0] = unbf((unsigned short)(pp.x & 0xffff));
        nn[1] = unbf((unsigned short)(pp.x >> 16));
        nn[2] = unbf((unsigned short)(pp.y & 0xffff));
        nn[3] = unbf((unsigned short)(pp.y >> 16));
        u[0]  = unbf((unsigned short)(pp.z & 0xffff));
        u[1]  = unbf((unsigned short)(pp.z >> 16));
        u[2]  = unbf((unsigned short)(pp.w & 0xffff));
        u[3]  = unbf((unsigned short)(pp.w >> 16));
#pragma unroll
        for (int rr = 0; rr < 4; ++rr) {
            const size_t o = ((size_t)(b0 + rr) * H + k) * L + j;
            out[o] = (1.0f - u[rr]) * nn[rr] + u[rr] * hidden[o];
        }
    }
}

// =====================================================================
// Fallback (R9 kernel, 295 us): used only if ws_size < WS_NEED.
// =====================================================================
constexpr int FB_OFF_XH    = LDS_WORDS;             // 7344
constexpr int FB_LDS_WORDS = FB_OFF_XH + 64 * 33;   // 9456 words

__global__ __launch_bounds__(256, 4)
void gcrnn_fallback(const float* __restrict__ hidden, const float* __restrict__ xin,
                    const float* __restrict__ Wrh, const float* __restrict__ Brh,
                    const float* __restrict__ Wri, const float* __restrict__ Bri,
                    const float* __restrict__ Wuh, const float* __restrict__ Buh,
                    const float* __restrict__ Wui, const float* __restrict__ Bui,
                    const float* __restrict__ Wnh, const float* __restrict__ Bnh,
                    const float* __restrict__ Wni, const float* __restrict__ Bni,
                    float* __restrict__ out)
{
    const int orig = blockIdx.x;
    const int j = (orig & 7) * (L / 8) + (orig >> 3);

    __shared__ float sL[FB_LDS_WORDS];
    unsigned* sLu = (unsigned*)sL;
    const int tb = threadIdx.x;

    {
        const int pr = tb >> 4;
        const int c0 = (tb & 15) * 4;
        const float* Wg[3] = {Wrh + (size_t)j * H * H, Wuh + (size_t)j * H * H,
                              Wnh + (size_t)j * H * H};
#pragma unroll
        for (int g = 0; g < 3; ++g) {
#pragma unroll
            for (int it = 0; it < 2; ++it) {
                const int p = it * 16 + pr;
                const f32x4 a = *(const f32x4*)(Wg[g] + (size_t)(2 * p) * H + c0);
                const f32x4 b = *(const f32x4*)(Wg[g] + (size_t)(2 * p + 1) * H + c0);
                uint4 w;
                w.x = pack2(a[0], b[0]); w.y = pack2(a[1], b[1]);
                w.z = pack2(a[2], b[2]); w.w = pack2(a[3], b[3]);
                *(uint4*)&sLu[g * W_GATE + p * WROW + c0] = w;
            }
        }
        if (tb < 64) {
            const int p = tb >> 4;
            const int ci = (tb & 15) * 4;
            const float* Wig[3] = {Wri + (size_t)j * F * H, Wui + (size_t)j * F * H,
                                   Wni + (size_t)j * F * H};
#pragma unroll
            for (int g = 0; g < 3; ++g) {
                const f32x4 a = *(const f32x4*)(Wig[g] + (size_t)(2 * p) * H + ci);
                const f32x4 b = *(const f32x4*)(Wig[g] + (size_t)(2 * p + 1) * H + ci);
                uint4 w;
                w.x = pack2(a[0], b[0]); w.y = pack2(a[1], b[1]);
                w.z = pack2(a[2], b[2]); w.w = pack2(a[3], b[3]);
                *(uint4*)&sLu[OFF_WIN + g * WIN_GATE + p * WROW + ci] = w;
            }
        }
#pragma unroll
        for (int it = 0; it < 8; ++it) {
            const int idx = tb + 256 * it;
            const int b = idx & 31, i = idx >> 5;
            sL[FB_OFF_XH + i * 33 + b] = hidden[(size_t)(b * H + i) * L + j];
        }
    }
    __syncthreads();

    const int lane = tb & 63;
    const int n    = tb >> 6;
    const int lc   = lane & 15;
    const int grp  = lane >> 4;
    const int col  = n * 16 + lc;

    bf16x8 aH[2][2], aI[2];
#pragma unroll
    for (int m = 0; m < 2; ++m) {
        const int b_ = m * 16 + lc;
#pragma unroll
        for (int ks = 0; ks < 2; ++ks)
#pragma unroll
            for (int e = 0; e < 8; ++e)
                aH[m][ks][e] = (__bf16)sL[FB_OFF_XH + (ks * 32 + grp * 8 + e) * 33 + b_];
        const size_t ibase = (size_t)b_ * F * L + j;
#pragma unroll
        for (int e = 0; e < 8; ++e) {
            const float v = (grp == 0) ? xin[ibase + (size_t)e * L] : 0.0f;
            aI[m][e] = (__bf16)v;
        }
    }
    __syncthreads();

    const size_t ko = (size_t)col * L + j;
    const float biR  = Brh[ko] + Bri[ko];
    const float biU  = Buh[ko] + Bui[ko];
    const float biNH = Bnh[ko];
    const float biNI = Bni[ko];

    auto rdH = [&](int g, int ks) -> bf16x8 {
        uint4 t;
        t.x = sLu[g * W_GATE + (ks * 16 + grp * 4 + 0) * WROW + col];
        t.y = sLu[g * W_GATE + (ks * 16 + grp * 4 + 1) * WROW + col];
        t.z = sLu[g * W_GATE + (ks * 16 + grp * 4 + 2) * WROW + col];
        t.w = sLu[g * W_GATE + (ks * 16 + grp * 4 + 3) * WROW + col];
        return __builtin_bit_cast(bf16x8, t);
    };
    auto rdI = [&](int g) -> bf16x8 {
        uint4 t;
        t.x = (grp == 0) ? sLu[OFF_WIN + g * WIN_GATE + 0 * WROW + col] : 0u;
        t.y = (grp == 0) ? sLu[OFF_WIN + g * WIN_GATE + 1 * WROW + col] : 0u;
        t.z = (grp == 0) ? sLu[OFF_WIN + g * WIN_GATE + 2 * WROW + col] : 0u;
        t.w = (grp == 0) ? sLu[OFF_WIN + g * WIN_GATE + 3 * WROW + col] : 0u;
        return __builtin_bit_cast(bf16x8, t);
    };

    const bf16x8 fR0 = rdH(0, 0), fR1 = rdH(0, 1);
    const bf16x8 fU0 = rdH(1, 0), fU1 = rdH(1, 1);
    const bf16x8 fN0 = rdH(2, 0), fN1 = rdH(2, 1);
    const bf16x8 fRI = rdI(0), fUI = rdI(1), fNI = rdI(2);

    f32x4 accR[2], accU[2], accN[2], accNI[2];
#pragma unroll
    for (int m = 0; m < 2; ++m) {
        accR[m]  = (f32x4){0.f, 0.f, 0.f, 0.f};
        accU[m]  = (f32x4){0.f, 0.f, 0.f, 0.f};
        accN[m]  = (f32x4){0.f, 0.f, 0.f, 0.f};
        accNI[m] = (f32x4){0.f, 0.f, 0.f, 0.f};
        accR[m] = __builtin_amdgcn_mfma_f32_16x16x32_bf16(aH[m][0], fR0, accR[m], 0, 0, 0);
        accR[m] = __builtin_amdgcn_mfma_f32_16x16x32_bf16(aH[m][1], fR1, accR[m], 0, 0, 0);
        accU[m] = __builtin_amdgcn_mfma_f32_16x16x32_bf16(aH[m][0], fU0, accU[m], 0, 0, 0);
        accU[m] = __builtin_amdgcn_mfma_f32_16x16x32_bf16(aH[m][1], fU1, accU[m], 0, 0, 0);
        accN[m] = __builtin_amdgcn_mfma_f32_16x16x32_bf16(aH[m][0], fN0, accN[m], 0, 0, 0);
        accN[m] = __builtin_amdgcn_mfma_f32_16x16x32_bf16(aH[m][1], fN1, accN[m], 0, 0, 0);
        accR[m]  = __builtin_amdgcn_mfma_f32_16x16x32_bf16(aI[m], fRI, accR[m], 0, 0, 0);
        accU[m]  = __builtin_amdgcn_mfma_f32_16x16x32_bf16(aI[m], fUI, accU[m], 0, 0, 0);
        accNI[m] = __builtin_amdgcn_mfma_f32_16x16x32_bf16(aI[m], fNI, accNI[m], 0, 0, 0);
    }

#pragma unroll
    for (int m = 0; m < 2; ++m)
#pragma unroll
        for (int rr = 0; rr < 4; ++rr) {
            const int b_ = m * 16 + grp * 4 + rr;
            const int w = FB_OFF_XH + col * 33 + b_;
            const float h = sL[w];
            const float rv = fsigmoid(accR[m][rr] + biR);
            const float uv = fsigmoid(accU[m][rr] + biU);
            const float nv = ftanh(rv * (accN[m][rr] + biNH) + accNI[m][rr] + biNI);
            sL[w] = (1.0f - uv) * nv + uv * h;
        }
    __syncthreads();

#pragma unroll
    for (int it = 0; it < 8; ++it) {
        const int idx = tb + 256 * it;
        const int b = idx & 31, k = idx >> 5;
        out[(size_t)(b * H + k) * L + j] = sL[FB_OFF_XH + k * 33 + b];
    }
}

} // namespace

extern "C" void kernel_launch(void* const* d_in, const int* in_sizes, int n_in,
                              void* d_out, int out_size, void* d_ws, size_t ws_size,
                              hipStream_t stream) {
    const float* hidden = (const float*)d_in[0];
    const float* xin    = (const float*)d_in[1];
    const float* Wrh    = (const float*)d_in[2];
    const float* Brh    = (const float*)d_in[3];
    const float* Wri    = (const float*)d_in[4];
    const float* Bri    = (const float*)d_in[5];
    const float* Wuh    = (const float*)d_in[6];
    const float* Buh    = (const float*)d_in[7];
    const float* Wui    = (const float*)d_in[8];
    const float* Bui    = (const float*)d_in[9];
    const float* Wnh    = (const float*)d_in[10];
    const float* Bnh    = (const float*)d_in[11];
    const float* Wni    = (const float*)d_in[12];
    const float* Bni    = (const float*)d_in[13];
    float* out = (float*)d_out;

    if (ws_size >= WS_NEED) {
        char* ws = (char*)d_ws;
        uint4* PA  = (uint4*)(ws + PA_OFF);
        float* PB  = (float*)(ws + PB_OFF);
        uint4* PNU = (uint4*)(ws + PNU_OFF);

        pre_pack<<<(L / 16) * 4, 256, 0, stream>>>(hidden, xin,
                                                   Brh, Bri, Buh, Bui, Bnh, Bni,
                                                   PA, PB);
        gcrnn_main<<<L, 256, 0, stream>>>(PA, PB,
                                          Wrh, Wuh, Wnh, Wri, Wui, Wni,
                                          PNU);
        post_blend<<<(L / 16) * 4, 256, 0, stream>>>(PNU, hidden, out);
    } else {
        gcrnn_fallback<<<L, 256, 0, stream>>>(hidden, xin,
                                              Wrh, Brh, Wri, Bri,
                                              Wuh, Buh, Wui, Bui,
                                              Wnh, Bnh, Wni, Bni,
                                              out);
    }
}